// Round 6
// baseline (1120.814 us; speedup 1.0000x reference)
//
#include <hip/hip_runtime.h>
#include <hip/hip_bf16.h>
#include <math.h>

// Activations: planar fp32 [B=2][plane=128][256*256] in ws; between layers NHWC bf16
// [B][256*256][136] (ch = ci*8 + o, padded 128->136 for 16B-aligned rows).
#define HW 65536
#define WID 256
#define NOR 8
#define PLANE_C (NOR * HW)          // 524288
#define PLANE_B (16 * NOR * HW)     // 8388608
#define NELEM (2 * PLANE_B)         // 16777216
#define BN_N 1048576.0f
#define NHWC_STRIDE 136             // shorts per pixel (128 real + 8 pad)

typedef __attribute__((ext_vector_type(8)))  short  short8;
typedef __attribute__((ext_vector_type(16))) float  float16;
typedef __attribute__((ext_vector_type(4)))  float  float4v;

__device__ __forceinline__ float bfv(const __hip_bfloat16 v) { return __bfloat162float(v); }

// ---- runtime dtype detection (bf16 vs fp32 storage), validated in R2/R3 ----
__global__ void detect_k(const void* __restrict__ x, int* __restrict__ flag) {
    __shared__ int bad;
    if (threadIdx.x == 0) bad = 0;
    __syncthreads();
    const __hip_bfloat16* p = (const __hip_bfloat16*)x;
    for (int i = threadIdx.x; i < 4096; i += 256) {
        float v = __bfloat162float(p[i]);
        if (!(fabsf(v) < 1e4f)) atomicOr(&bad, 1);
    }
    __syncthreads();
    if (threadIdx.x == 0) *flag = bad ? 0 : 1;
}

__global__ void cvt_k(const void* __restrict__ in, float* __restrict__ out, int n,
                      const int* __restrict__ flag) {
    int i = blockIdx.x * blockDim.x + threadIdx.x;
    if (i >= n) return;
    if (*flag)
        out[i] = __bfloat162float(((const __hip_bfloat16*)in)[i]);
    else
        out[i] = ((const float*)in)[i];
}

// ---- bilinear kernel rotation (bit-identical to R2..R5, which passed) ----
__device__ float rot_sample(const float* __restrict__ W, int k, float theta, int i, int j) {
    float c = 0.5f * (float)(k - 1);
    float ys = (float)i - c, xs = (float)j - c;
    float cs = cosf(theta), sn = sinf(theta);
    float sy = cs * ys - sn * xs + c;
    float sx = sn * ys + cs * xs + c;
    float fy = floorf(sy), fx = floorf(sx);
    int y0 = (int)fy, x0 = (int)fx;
    float wy = sy - fy, wx = sx - fx;
    float v00 = (y0 >= 0 && y0 < k && x0 >= 0 && x0 < k)                 ? W[y0 * k + x0]           : 0.f;
    float v01 = (y0 >= 0 && y0 < k && x0 + 1 >= 0 && x0 + 1 < k)         ? W[y0 * k + x0 + 1]       : 0.f;
    float v10 = (y0 + 1 >= 0 && y0 + 1 < k && x0 >= 0 && x0 < k)         ? W[(y0 + 1) * k + x0]     : 0.f;
    float v11 = (y0 + 1 >= 0 && y0 + 1 < k && x0 + 1 >= 0 && x0 + 1 < k) ? W[(y0 + 1) * k + x0 + 1] : 0.f;
    return v00 * (1 - wy) * (1 - wx) + v01 * (1 - wy) * wx
         + v10 * wy * (1 - wx) + v11 * wy * wx;
}

__device__ __forceinline__ float theta_of(int m) {
    return (6.2831855f * (float)m) / 8.0f;
}

__device__ __forceinline__ int mirror(int i) {
    i = i < 0 ? -i : i;
    return i >= WID ? (2 * WID - 2 - i) : i;
}

// ---- weight pack: lift B [n=c*8+o][k=ci*49+dy*7+dx, padded to 160] bf16 ----
__global__ void pack_blift_k(const float* __restrict__ lw, __hip_bfloat16* __restrict__ B) {
    int idx = blockIdx.x * 256 + threadIdx.x;
    if (idx >= 128 * 160) return;
    int n = idx / 160, k = idx % 160;
    float v = 0.f;
    if (k < 147) {
        int c = n >> 3, o = n & 7;
        int ci = k / 49, s = k % 49;
        v = rot_sample(lw + (c * 3 + ci) * 49, 7, theta_of(o), s / 7, s % 7);
    }
    B[idx] = __float2bfloat16(v);
}

// ---- weight pack: gconv Bg[s=dy*5+dx][n=co*8+m][ch=ci*8+o] bf16 ----
__global__ void pack_bg_k(const float* __restrict__ w, __hip_bfloat16* __restrict__ Bg) {
    int idx = blockIdx.x * 256 + threadIdx.x;
    if (idx >= 25 * 128 * 128) return;
    int s = idx >> 14;
    int r = idx & 16383;
    int n = r >> 7, ch = r & 127;
    int co = n >> 3, m = n & 7, ci = ch >> 3, o = ch & 7;
    int oo = (o - m + 8) & 7;
    float v = rot_sample(w + ((co * 16 + ci) * 8 + oo) * 25, 5, theta_of(m), s / 5, s % 5);
    Bg[idx] = __float2bfloat16(v);
}

// ---- weight pack: 1x1 B1[n=co*8+m][ch=ci*8+o] bf16 ----
__global__ void pack_b1_k(const float* __restrict__ w4, __hip_bfloat16* __restrict__ B1) {
    int idx = blockIdx.x * 256 + threadIdx.x;
    if (idx >= 128 * 128) return;
    int n = idx >> 7, ch = idx & 127;
    int co = n >> 3, m = n & 7, ci = ch >> 3, o = ch & 7;
    B1[idx] = __float2bfloat16(w4[(co * 16 + ci) * 8 + ((o - m + 8) & 7)]);
}

// ---- lift im2col (one batch): A[px][160] bf16, k = ci*49 + dy*7 + dx ----
__global__ void im2col_lift_k(const float* __restrict__ xb, __hip_bfloat16* __restrict__ A) {
    int idx = blockIdx.x * 256 + threadIdx.x;
    if (idx >= HW * 160) return;
    int px = idx / 160, k = idx % 160;
    float v = 0.f;
    if (k < 147) {
        int ci = k / 49, s = k % 49;
        int gy = mirror((px >> 8) + s / 7 - 3);
        int gx = mirror((px & 255) + s % 7 - 3);
        v = xb[ci * HW + gy * WID + gx];
    }
    A[idx] = __float2bfloat16(v);
}

// ---- MFMA fragment conventions (verified R3..R5):
// A (32x32x16): lane holds A[m=lane&31][k=(lane>>5)*8+j]
// B: lane holds B[k=(lane>>5)*8+j][n=lane&31]
// C/D: col=lane&31, row=(reg&3)+8*(reg>>2)+4*(lane>>5)

// Shared epilogue helper: per-lane BN partial sums from the 8 accs, reduced
// across the 16 lanes sharing channel c = n>>3 (xor masks 1,2,4,32), into
// LDS sred[32] (sum 0..15, sumsq 16..31). Caller barriers + global atomics.
__device__ __forceinline__ void stats_reduce(const float16* acc, int lane, int l31,
                                             float* sred) {
#pragma unroll
    for (int nt = 0; nt < 4; nt++) {
        float sv = 0.f, s2v = 0.f;
#pragma unroll
        for (int g = 0; g < 2; g++)
#pragma unroll
            for (int r = 0; r < 16; r++) {
                float v = acc[g * 4 + nt][r];
                sv += v;
                s2v += v * v;
            }
#pragma unroll
        for (int off = 1; off <= 4; off <<= 1) {
            sv += __shfl_xor(sv, off);
            s2v += __shfl_xor(s2v, off);
        }
        sv += __shfl_xor(sv, 32);
        s2v += __shfl_xor(s2v, 32);
        if ((lane & 39) == 0) {  // l31&7==0 && half==0 -> lanes 0,8,16,24
            int c = nt * 4 + (l31 >> 3);
            atomicAdd(&sred[c], sv);
            atomicAdd(&sred[16 + c], s2v);
        }
    }
}

// lift GEMM: M=65536 (one b), K=160 (10 ksteps), N=128. out pre-offset by b.
__global__ __launch_bounds__(256, 2) void lift_gemm_k(const __hip_bfloat16* __restrict__ Ah,
                                                      const __hip_bfloat16* __restrict__ Bh,
                                                      float* __restrict__ out,
                                                      float* __restrict__ stats) {
    __shared__ float sred[32];
    const short* A = (const short*)Ah;
    const short* B = (const short*)Bh;
    int tid = threadIdx.x;
    if (tid < 32) sred[tid] = 0.f;
    __syncthreads();
    int wave = tid >> 6, lane = tid & 63;
    int l31 = lane & 31, half = lane >> 5;
    int p0 = blockIdx.x * 256 + wave * 64;
    float16 acc[8];
#pragma unroll
    for (int i = 0; i < 8; i++) acc[i] = (float16)0.f;
    const short* a0p = A + (size_t)(p0 + l31) * 160 + half * 8;
    const short* a1p = a0p + 32 * 160;
    const short* bp  = B + (size_t)l31 * 160 + half * 8;
#pragma unroll
    for (int ks = 0; ks < 10; ks++) {
        short8 a0 = *(const short8*)(a0p + ks * 16);
        short8 a1 = *(const short8*)(a1p + ks * 16);
#pragma unroll
        for (int nt = 0; nt < 4; nt++) {
            short8 bb = *(const short8*)(bp + nt * 32 * 160 + ks * 16);
            acc[nt]     = __builtin_amdgcn_mfma_f32_32x32x16_bf16(a0, bb, acc[nt], 0, 0, 0);
            acc[4 + nt] = __builtin_amdgcn_mfma_f32_32x32x16_bf16(a1, bb, acc[4 + nt], 0, 0, 0);
        }
    }
#pragma unroll
    for (int g = 0; g < 2; g++)
#pragma unroll
        for (int nt = 0; nt < 4; nt++) {
            int n = nt * 32 + l31;
#pragma unroll
            for (int r4 = 0; r4 < 4; r4++) {
                int base = 8 * r4 + 4 * half;
                float4v v;
                v[0] = acc[g * 4 + nt][r4 * 4 + 0];
                v[1] = acc[g * 4 + nt][r4 * 4 + 1];
                v[2] = acc[g * 4 + nt][r4 * 4 + 2];
                v[3] = acc[g * 4 + nt][r4 * 4 + 3];
                __builtin_nontemporal_store(v, (float4v*)(out + (size_t)n * HW + p0 + g * 32 + base));
            }
        }
    stats_reduce(acc, lane, l31, sred);
    __syncthreads();
    if (tid < 16) {
        atomicAdd(&stats[tid * 2], sred[tid]);
        atomicAdd(&stats[tid * 2 + 1], sred[16 + tid]);
    }
}

// gconv GEMM R6: 512 blocks (XCD band swizzle), block = 16x16 px x 128 n.
// A-halo (20x20 px, K-split into two 64-ch halves of 128 B/px = 50 KB) staged
// in LDS once per half -> inner 25-shift loop has NO global A access and NO
// mirror. B read directly from global (identical 8 KB slabs across all waves
// -> L1/L2-hot). Only 2 barrier pairs per kernel. BN stats fused in epilogue;
// planar output written nontemporal (no L2 write-allocate pollution).
__global__ __launch_bounds__(256, 2) void gconv_mfma_k(const __hip_bfloat16* __restrict__ nh,
                                                       const __hip_bfloat16* __restrict__ Bgh,
                                                       float* __restrict__ out,
                                                       float* __restrict__ stats) {
    __shared__ short As[8 * 400 * 8];   // 51200 B: [kc 0..7][px_l 0..399][8 shorts]
    __shared__ float sred[32];
    const short* nhwc = (const short*)nh;
    const short* Bg = (const short*)Bgh;
    int bid = blockIdx.x;
    int xcd = bid & 7, q = bid >> 3;
    int b = xcd >> 2, band = xcd & 3;
    int tx0 = (q & 15) << 4;
    int ty0 = (band << 6) + ((q >> 4) << 4);
    int tid = threadIdx.x;
    if (tid < 32) sred[tid] = 0.f;
    int wave = tid >> 6, lane = tid & 63;
    int l31 = lane & 31, half = lane >> 5, lx = lane & 15, yy = l31 >> 4;
    float16 acc[8];
#pragma unroll
    for (int i = 0; i < 8; i++) acc[i] = (float16)0.f;
    const size_t bbase = (size_t)b * HW;
    int yl0 = (wave << 2) + yy + 2;   // local y of group0 (pre-dy); group1 = +2
    int xl0 = lx + 2;

    for (int kh = 0; kh < 2; kh++) {
        __syncthreads();   // protect As reuse (and sred init at kh=0)
        for (int i = tid; i < 3200; i += 256) {
            int kc = i / 400, p = i - kc * 400;
            int yl = p / 20, xl = p - yl * 20;
            int gy = mirror(ty0 - 2 + yl);
            int gx = mirror(tx0 - 2 + xl);
            *(short8*)&As[(kc * 400 + p) * 8] =
                *(const short8*)(nhwc + (bbase + gy * WID + gx) * NHWC_STRIDE + kh * 64 + kc * 8);
        }
        __syncthreads();
        const short* bkh = Bg + kh * 64;
        for (int s = 0; s < 25; s++) {
            int dy = s / 5 - 2, dx = s % 5 - 2;
            int pxa = (yl0 + dy) * 20 + xl0 + dx;
            const short* brow = bkh + (size_t)(s * 128 + l31) * 128;
#pragma unroll
            for (int ks = 0; ks < 4; ks++) {
                int kc = ks * 2 + half;
                short8 a0 = *(const short8*)&As[(kc * 400 + pxa) * 8];
                short8 a1 = *(const short8*)&As[(kc * 400 + pxa + 40) * 8];
                const short* bksp = brow + kc * 8;
#pragma unroll
                for (int nt = 0; nt < 4; nt++) {
                    short8 bb = *(const short8*)(bksp + nt * 32 * 128);
                    acc[nt]     = __builtin_amdgcn_mfma_f32_32x32x16_bf16(a0, bb, acc[nt], 0, 0, 0);
                    acc[4 + nt] = __builtin_amdgcn_mfma_f32_32x32x16_bf16(a1, bb, acc[4 + nt], 0, 0, 0);
                }
            }
        }
    }

    const size_t outb = (size_t)b * PLANE_B;
#pragma unroll
    for (int g = 0; g < 2; g++) {
        int ybase = ty0 + (wave << 2) + g * 2;
#pragma unroll
        for (int nt = 0; nt < 4; nt++) {
            int n = nt * 32 + l31;
            float* plane = out + outb + (size_t)n * HW;
#pragma unroll
            for (int r4 = 0; r4 < 4; r4++) {
                int base = 8 * r4 + 4 * half;
                float4v v;
                v[0] = acc[g * 4 + nt][r4 * 4 + 0];
                v[1] = acc[g * 4 + nt][r4 * 4 + 1];
                v[2] = acc[g * 4 + nt][r4 * 4 + 2];
                v[3] = acc[g * 4 + nt][r4 * 4 + 3];
                __builtin_nontemporal_store(v,
                    (float4v*)(plane + (size_t)(ybase + (base >> 4)) * WID + tx0 + (base & 15)));
            }
        }
    }
    stats_reduce(acc, lane, l31, sred);
    __syncthreads();
    if (tid < 16) {
        atomicAdd(&stats[tid * 2], sred[tid]);
        atomicAdd(&stats[tid * 2 + 1], sred[16 + tid]);
    }
}

// 1x1 gconv GEMM: K=128 straight from NHWC; fused BN stats.
__global__ __launch_bounds__(256, 2) void conv1x1_gemm_k(const __hip_bfloat16* __restrict__ nh,
                                                         const __hip_bfloat16* __restrict__ B1h,
                                                         float* __restrict__ out,
                                                         float* __restrict__ stats) {
    __shared__ float sred[32];
    const short* nhwc = (const short*)nh;
    const short* B1 = (const short*)B1h;
    int tid = threadIdx.x;
    if (tid < 32) sred[tid] = 0.f;
    __syncthreads();
    int b = blockIdx.y;
    int wave = tid >> 6, lane = tid & 63;
    int l31 = lane & 31, half = lane >> 5;
    int p0 = blockIdx.x * 256 + wave * 64;
    float16 acc[8];
#pragma unroll
    for (int i = 0; i < 8; i++) acc[i] = (float16)0.f;
    const short* a0p = nhwc + ((size_t)b * HW + p0 + l31) * NHWC_STRIDE + half * 8;
    const short* a1p = a0p + 32 * NHWC_STRIDE;
    const short* bp  = B1 + (size_t)l31 * 128 + half * 8;
#pragma unroll
    for (int ks = 0; ks < 8; ks++) {
        short8 a0 = *(const short8*)(a0p + ks * 16);
        short8 a1 = *(const short8*)(a1p + ks * 16);
#pragma unroll
        for (int nt = 0; nt < 4; nt++) {
            short8 bb = *(const short8*)(bp + nt * 32 * 128 + ks * 16);
            acc[nt]     = __builtin_amdgcn_mfma_f32_32x32x16_bf16(a0, bb, acc[nt], 0, 0, 0);
            acc[4 + nt] = __builtin_amdgcn_mfma_f32_32x32x16_bf16(a1, bb, acc[4 + nt], 0, 0, 0);
        }
    }
    float* outb = out + (size_t)b * PLANE_B;
#pragma unroll
    for (int g = 0; g < 2; g++)
#pragma unroll
        for (int nt = 0; nt < 4; nt++) {
            int n = nt * 32 + l31;
#pragma unroll
            for (int r4 = 0; r4 < 4; r4++) {
                int base = 8 * r4 + 4 * half;
                float4v v;
                v[0] = acc[g * 4 + nt][r4 * 4 + 0];
                v[1] = acc[g * 4 + nt][r4 * 4 + 1];
                v[2] = acc[g * 4 + nt][r4 * 4 + 2];
                v[3] = acc[g * 4 + nt][r4 * 4 + 3];
                __builtin_nontemporal_store(v,
                    (float4v*)(outb + (size_t)n * HW + p0 + g * 32 + base));
            }
        }
    stats_reduce(acc, lane, l31, sred);
    __syncthreads();
    if (tid < 16) {
        atomicAdd(&stats[tid * 2], sred[tid]);
        atomicAdd(&stats[tid * 2 + 1], sred[16 + tid]);
    }
}

// ---- BN finalize ----
__global__ void zero_k(float* p, int n) {
    int i = blockIdx.x * blockDim.x + threadIdx.x;
    if (i < n) p[i] = 0.f;
}

__global__ void finalize_k(const float* __restrict__ stats, const float* __restrict__ g,
                           const float* __restrict__ beta, float* __restrict__ ss) {
    int c = threadIdx.x;
    if (c >= 16) return;
    float mean = stats[c * 2] / BN_N;
    float var = stats[c * 2 + 1] / BN_N - mean * mean;
    float sc = g[c] * rsqrtf(var + 1e-5f);
    ss[c * 2] = sc;
    ss[c * 2 + 1] = beta[c] - mean * sc;
}

// ---- fused BN+ReLU + planar->NHWC(bf16, padded) repack ----
__global__ void repack_k(const float* __restrict__ planar, const float* __restrict__ ss,
                         __hip_bfloat16* __restrict__ nhwc) {
    __shared__ __hip_bfloat16 ls[128 * NHWC_STRIDE];
    int b = blockIdx.y;
    int px0 = blockIdx.x * 128;
    for (int i = threadIdx.x; i < 128 * 8; i += 256)
        ls[(i >> 3) * NHWC_STRIDE + 128 + (i & 7)] = __float2bfloat16(0.f);
    int px = threadIdx.x & 127;
    int choff = threadIdx.x >> 7;
    const float* pb = planar + (size_t)b * PLANE_B + px0 + px;
    for (int chb = 0; chb < 64; chb++) {
        int ch = chb * 2 + choff;
        int c = ch >> 3;
        float v = pb[(size_t)ch * HW];
        v = v * ss[c * 2] + ss[c * 2 + 1];
        v = v > 0.f ? v : 0.f;
        ls[px * NHWC_STRIDE + ch] = __float2bfloat16(v);
    }
    __syncthreads();
    short* outp = (short*)nhwc + ((size_t)b * HW + px0) * NHWC_STRIDE;
    const short* lsp = (const short*)ls;
    for (int i = threadIdx.x; i < 128 * 17; i += 256) {
        int p = i / 17, seg = i % 17;
        *(short8*)(outp + (size_t)p * NHWC_STRIDE + seg * 8) =
            *(const short8*)(lsp + p * NHWC_STRIDE + seg * 8);
    }
}

// ---- BN+ReLU on conv4, max over m, final 1x1 + sigmoid; dtype-flagged write ----
__global__ void final_k(const float* __restrict__ in, const float* __restrict__ ss,
                        const float* __restrict__ fw, void* __restrict__ out,
                        const int* __restrict__ flag) {
    int i = blockIdx.x * blockDim.x + threadIdx.x;
    int b = i >> 16, pix = i & 65535;
    float acc = 0.f;
#pragma unroll
    for (int co = 0; co < 16; co++) {
        float sc = ss[co * 2], sh = ss[co * 2 + 1];
        float mx = 0.f;
        const float* p = in + (size_t)b * PLANE_B + (size_t)co * PLANE_C + pix;
#pragma unroll
        for (int m = 0; m < 8; m++) mx = fmaxf(mx, p[m * HW] * sc + sh);
        acc = fmaf(fw[co], mx, acc);
    }
    float r = 1.f / (1.f + expf(-acc));
    if (*flag)
        ((__hip_bfloat16*)out)[i] = __float2bfloat16(r);
    else
        ((float*)out)[i] = r;
}

extern "C" void kernel_launch(void* const* d_in, const int* in_sizes, int n_in,
                              void* d_out, int out_size, void* d_ws, size_t ws_size,
                              hipStream_t stream) {
    float* ws = (float*)d_ws;
    float* planar = ws;                                        // 16,777,216 f
    __hip_bfloat16* nhwc = (__hip_bfloat16*)(ws + 16777216);   // 17,825,792 bf16
    __hip_bfloat16* Alift = (__hip_bfloat16*)(ws + 25690112);  // 10,485,760 bf16
    __hip_bfloat16* Bg    = (__hip_bfloat16*)(ws + 30932992);  // 409,600 bf16
    __hip_bfloat16* Blift = (__hip_bfloat16*)(ws + 31137792);  // 20,480 bf16
    __hip_bfloat16* B1    = (__hip_bfloat16*)(ws + 31148032);  // 16,384 bf16
    float* xF  = ws + 31156224;        // 393216
    float* lwF = xF + 393216;          // 2352
    float* w1F = lwF + 2352;           // 102400
    float* w2F = w1F + 102400;
    float* w3F = w2F + 102400;
    float* w4F = w3F + 102400;         // 2048
    float* fwF = w4F + 2048;           // 16
    float* gbF = fwF + 16;             // 160
    float* stats = gbF + 160;          // 32
    float* ss    = stats + 32;         // 32
    int*   flag  = (int*)(ss + 32);

    detect_k<<<1, 256, 0, stream>>>(d_in[0], flag);
    {
        float* dsts[17] = {xF, lwF, w1F, w2F, w3F, w4F, fwF,
                           gbF + 0,  gbF + 16, gbF + 32, gbF + 48, gbF + 64,
                           gbF + 80, gbF + 96, gbF + 112, gbF + 128, gbF + 144};
        for (int i = 0; i < 17; i++) {
            int n = in_sizes[i];
            cvt_k<<<(n + 255) / 256, 256, 0, stream>>>(d_in[i], dsts[i], n, flag);
        }
    }

    // ---- lift: pack B, per-batch im2col + GEMM (stats fused) ----
    pack_blift_k<<<(128 * 160 + 255) / 256, 256, 0, stream>>>(lwF, Blift);
    zero_k<<<1, 64, 0, stream>>>(stats, 32);
    for (int b = 0; b < 2; b++) {
        im2col_lift_k<<<(HW * 160 + 255) / 256, 256, 0, stream>>>(xF + (size_t)b * 3 * HW, Alift);
        lift_gemm_k<<<256, 256, 0, stream>>>(Alift, Blift, planar + (size_t)b * PLANE_B, stats);
    }
    finalize_k<<<1, 64, 0, stream>>>(stats, gbF + 0, gbF + 16, ss);
    repack_k<<<dim3(512, 2), 256, 0, stream>>>(planar, ss, nhwc);

    // ---- gconv 1..3 (stats fused) ----
    float* wlist[3] = {w1F, w2F, w3F};
    for (int l = 0; l < 3; l++) {
        pack_bg_k<<<(25 * 128 * 128 + 255) / 256, 256, 0, stream>>>(wlist[l], Bg);
        zero_k<<<1, 64, 0, stream>>>(stats, 32);
        gconv_mfma_k<<<512, 256, 0, stream>>>(nhwc, Bg, planar, stats);
        finalize_k<<<1, 64, 0, stream>>>(stats, gbF + 32 * (l + 1), gbF + 32 * (l + 1) + 16, ss);
        repack_k<<<dim3(512, 2), 256, 0, stream>>>(planar, ss, nhwc);
    }

    // ---- conv4 (1x1, stats fused; BN/ReLU applied in final_k) ----
    pack_b1_k<<<(128 * 128 + 255) / 256, 256, 0, stream>>>(w4F, B1);
    zero_k<<<1, 64, 0, stream>>>(stats, 32);
    conv1x1_gemm_k<<<dim3(256, 2), 256, 0, stream>>>(nhwc, B1, planar, stats);
    finalize_k<<<1, 64, 0, stream>>>(stats, gbF + 128, gbF + 144, ss);

    // ---- max-project + final 1x1 + sigmoid ----
    final_k<<<(2 * HW) / 256, 256, 0, stream>>>(planar, ss, fwF, d_out, flag);
}

// Round 8
// 1030.250 us; speedup vs baseline: 1.0879x; 1.0879x over previous
//
#include <hip/hip_runtime.h>
#include <hip/hip_bf16.h>
#include <math.h>

// Activations: planar fp32 [B=2][plane=128][256*256] in ws; between layers NHWC bf16
// [B][256*256][136] (ch = ci*8 + o, padded 128->136 for 16B-aligned rows).
#define HW 65536
#define WID 256
#define NOR 8
#define PLANE_C (NOR * HW)          // 524288
#define PLANE_B (16 * NOR * HW)     // 8388608
#define NELEM (2 * PLANE_B)         // 16777216
#define BN_N 1048576.0f
#define NHWC_STRIDE 136             // shorts per pixel (128 real + 8 pad)

typedef __attribute__((ext_vector_type(8)))  short  short8;
typedef __attribute__((ext_vector_type(16))) float  float16;
typedef __attribute__((ext_vector_type(4)))  float  float4v;

// ---- runtime dtype detection (bf16 vs fp32 storage), validated in R2/R3 ----
__global__ void detect_k(const void* __restrict__ x, int* __restrict__ flag) {
    __shared__ int bad;
    if (threadIdx.x == 0) bad = 0;
    __syncthreads();
    const __hip_bfloat16* p = (const __hip_bfloat16*)x;
    for (int i = threadIdx.x; i < 4096; i += 256) {
        float v = __bfloat162float(p[i]);
        if (!(fabsf(v) < 1e4f)) atomicOr(&bad, 1);
    }
    __syncthreads();
    if (threadIdx.x == 0) *flag = bad ? 0 : 1;
}

// ---- single-dispatch conversion of all 17 inputs into contiguous fp32 region ----
// Sizes (R7 bug fixed: w1/w2/w3 are 51,200 NOT 102,400):
// x 393216 | lw 2352 | w1 51200 | w2 51200 | w3 51200 | w4 2048 | fw 16 | 10x16
#define CVT_TOTAL 551392
__global__ void cvt_all_k(const void* p0, const void* p1, const void* p2, const void* p3,
                          const void* p4, const void* p5, const void* p6, const void* p7,
                          const void* p8, const void* p9, const void* p10, const void* p11,
                          const void* p12, const void* p13, const void* p14, const void* p15,
                          const void* p16, float* __restrict__ dst, const int* __restrict__ flag) {
    int i = blockIdx.x * 512 + threadIdx.x;
    if (i >= CVT_TOTAL) return;
    const void* src; int off;
    if      (i < 393216) { src = p0;  off = 0; }
    else if (i < 395568) { src = p1;  off = 393216; }
    else if (i < 446768) { src = p2;  off = 395568; }
    else if (i < 497968) { src = p3;  off = 446768; }
    else if (i < 549168) { src = p4;  off = 497968; }
    else if (i < 551216) { src = p5;  off = 549168; }
    else if (i < 551232) { src = p6;  off = 551216; }
    else if (i < 551248) { src = p7;  off = 551232; }
    else if (i < 551264) { src = p8;  off = 551248; }
    else if (i < 551280) { src = p9;  off = 551264; }
    else if (i < 551296) { src = p10; off = 551280; }
    else if (i < 551312) { src = p11; off = 551296; }
    else if (i < 551328) { src = p12; off = 551312; }
    else if (i < 551344) { src = p13; off = 551328; }
    else if (i < 551360) { src = p14; off = 551344; }
    else if (i < 551376) { src = p15; off = 551360; }
    else                 { src = p16; off = 551376; }
    int j = i - off;
    dst[i] = (*flag) ? __bfloat162float(((const __hip_bfloat16*)src)[j])
                     : ((const float*)src)[j];
}

// ---- bilinear kernel rotation (bit-identical to R2..R6, which passed) ----
__device__ float rot_sample(const float* __restrict__ W, int k, float theta, int i, int j) {
    float c = 0.5f * (float)(k - 1);
    float ys = (float)i - c, xs = (float)j - c;
    float cs = cosf(theta), sn = sinf(theta);
    float sy = cs * ys - sn * xs + c;
    float sx = sn * ys + cs * xs + c;
    float fy = floorf(sy), fx = floorf(sx);
    int y0 = (int)fy, x0 = (int)fx;
    float wy = sy - fy, wx = sx - fx;
    float v00 = (y0 >= 0 && y0 < k && x0 >= 0 && x0 < k)                 ? W[y0 * k + x0]           : 0.f;
    float v01 = (y0 >= 0 && y0 < k && x0 + 1 >= 0 && x0 + 1 < k)         ? W[y0 * k + x0 + 1]       : 0.f;
    float v10 = (y0 + 1 >= 0 && y0 + 1 < k && x0 >= 0 && x0 < k)         ? W[(y0 + 1) * k + x0]     : 0.f;
    float v11 = (y0 + 1 >= 0 && y0 + 1 < k && x0 + 1 >= 0 && x0 + 1 < k) ? W[(y0 + 1) * k + x0 + 1] : 0.f;
    return v00 * (1 - wy) * (1 - wx) + v01 * (1 - wy) * wx
         + v10 * wy * (1 - wx) + v11 * wy * wx;
}

__device__ __forceinline__ float theta_of(int m) {
    return (6.2831855f * (float)m) / 8.0f;
}

__device__ __forceinline__ int mirror(int i) {
    i = i < 0 ? -i : i;
    return i >= WID ? (2 * WID - 2 - i) : i;
}

// ---- weight packs (stats-zero folded in) ----
__global__ void pack_blift_k(const float* __restrict__ lw, __hip_bfloat16* __restrict__ B,
                             float* __restrict__ stats) {
    int idx = blockIdx.x * 256 + threadIdx.x;
    if (idx < 32) stats[idx] = 0.f;
    if (idx >= 128 * 160) return;
    int n = idx / 160, k = idx % 160;
    float v = 0.f;
    if (k < 147) {
        int c = n >> 3, o = n & 7;
        int ci = k / 49, s = k % 49;
        v = rot_sample(lw + (c * 3 + ci) * 49, 7, theta_of(o), s / 7, s % 7);
    }
    B[idx] = __float2bfloat16(v);
}

__global__ void pack_bg_k(const float* __restrict__ w, __hip_bfloat16* __restrict__ Bg,
                          float* __restrict__ stats) {
    int idx = blockIdx.x * 256 + threadIdx.x;
    if (idx < 32) stats[idx] = 0.f;
    if (idx >= 25 * 128 * 128) return;
    int s = idx >> 14;
    int r = idx & 16383;
    int n = r >> 7, ch = r & 127;
    int co = n >> 3, m = n & 7, ci = ch >> 3, o = ch & 7;
    int oo = (o - m + 8) & 7;
    float v = rot_sample(w + ((co * 16 + ci) * 8 + oo) * 25, 5, theta_of(m), s / 5, s % 5);
    Bg[idx] = __float2bfloat16(v);
}

__global__ void pack_b1_k(const float* __restrict__ w4, __hip_bfloat16* __restrict__ B1,
                          float* __restrict__ stats) {
    int idx = blockIdx.x * 256 + threadIdx.x;
    if (idx < 32) stats[idx] = 0.f;
    if (idx >= 128 * 128) return;
    int n = idx >> 7, ch = idx & 127;
    int co = n >> 3, m = n & 7, ci = ch >> 3, o = ch & 7;
    B1[idx] = __float2bfloat16(w4[(co * 16 + ci) * 8 + ((o - m + 8) & 7)]);
}

// ---- lift im2col (one batch): A[px][160] bf16, k = ci*49 + dy*7 + dx ----
__global__ void im2col_lift_k(const float* __restrict__ xb, __hip_bfloat16* __restrict__ A) {
    int idx = blockIdx.x * 256 + threadIdx.x;
    if (idx >= HW * 160) return;
    int px = idx / 160, k = idx % 160;
    float v = 0.f;
    if (k < 147) {
        int ci = k / 49, s = k % 49;
        int gy = mirror((px >> 8) + s / 7 - 3);
        int gx = mirror((px & 255) + s % 7 - 3);
        v = xb[ci * HW + gy * WID + gx];
    }
    A[idx] = __float2bfloat16(v);
}

// ---- MFMA fragment conventions (verified R3..R6):
// A (32x32x16): lane holds A[m=lane&31][k=(lane>>5)*8+j]
// B: lane holds B[k=(lane>>5)*8+j][n=lane&31]
// C/D: col=lane&31, row=(reg&3)+8*(reg>>2)+4*(lane>>5)

// BN partial-sum reduction (8-acc variant) into sred[32].
__device__ __forceinline__ void stats_reduce8(const float16* acc, int lane, int l31,
                                              float* sred) {
#pragma unroll
    for (int nt = 0; nt < 4; nt++) {
        float sv = 0.f, s2v = 0.f;
#pragma unroll
        for (int g = 0; g < 2; g++)
#pragma unroll
            for (int r = 0; r < 16; r++) {
                float v = acc[g * 4 + nt][r];
                sv += v;
                s2v += v * v;
            }
#pragma unroll
        for (int off = 1; off <= 4; off <<= 1) {
            sv += __shfl_xor(sv, off);
            s2v += __shfl_xor(s2v, off);
        }
        sv += __shfl_xor(sv, 32);
        s2v += __shfl_xor(s2v, 32);
        if ((lane & 39) == 0) {
            int c = nt * 4 + (l31 >> 3);
            atomicAdd(&sred[c], sv);
            atomicAdd(&sred[16 + c], s2v);
        }
    }
}

// lift GEMM: M=65536 (one b), K=160 (10 ksteps), N=128. out pre-offset by b.
__global__ __launch_bounds__(256, 2) void lift_gemm_k(const __hip_bfloat16* __restrict__ Ah,
                                                      const __hip_bfloat16* __restrict__ Bh,
                                                      float* __restrict__ out,
                                                      float* __restrict__ stats) {
    __shared__ float sred[32];
    const short* A = (const short*)Ah;
    const short* B = (const short*)Bh;
    int tid = threadIdx.x;
    if (tid < 32) sred[tid] = 0.f;
    __syncthreads();
    int wave = tid >> 6, lane = tid & 63;
    int l31 = lane & 31, half = lane >> 5;
    int p0 = blockIdx.x * 256 + wave * 64;
    float16 acc[8];
#pragma unroll
    for (int i = 0; i < 8; i++) acc[i] = (float16)0.f;
    const short* a0p = A + (size_t)(p0 + l31) * 160 + half * 8;
    const short* a1p = a0p + 32 * 160;
    const short* bp  = B + (size_t)l31 * 160 + half * 8;
#pragma unroll
    for (int ks = 0; ks < 10; ks++) {
        short8 a0 = *(const short8*)(a0p + ks * 16);
        short8 a1 = *(const short8*)(a1p + ks * 16);
#pragma unroll
        for (int nt = 0; nt < 4; nt++) {
            short8 bb = *(const short8*)(bp + nt * 32 * 160 + ks * 16);
            acc[nt]     = __builtin_amdgcn_mfma_f32_32x32x16_bf16(a0, bb, acc[nt], 0, 0, 0);
            acc[4 + nt] = __builtin_amdgcn_mfma_f32_32x32x16_bf16(a1, bb, acc[4 + nt], 0, 0, 0);
        }
    }
#pragma unroll
    for (int g = 0; g < 2; g++)
#pragma unroll
        for (int nt = 0; nt < 4; nt++) {
            int n = nt * 32 + l31;
#pragma unroll
            for (int r4 = 0; r4 < 4; r4++) {
                int base = 8 * r4 + 4 * half;
                float4v v;
                v[0] = acc[g * 4 + nt][r4 * 4 + 0];
                v[1] = acc[g * 4 + nt][r4 * 4 + 1];
                v[2] = acc[g * 4 + nt][r4 * 4 + 2];
                v[3] = acc[g * 4 + nt][r4 * 4 + 3];
                __builtin_nontemporal_store(v, (float4v*)(out + (size_t)n * HW + p0 + g * 32 + base));
            }
        }
    stats_reduce8(acc, lane, l31, sred);
    __syncthreads();
    if (tid < 16) {
        atomicAdd(&stats[tid * 2], sred[tid]);
        atomicAdd(&stats[tid * 2 + 1], sred[16 + tid]);
    }
}

// gconv GEMM R8 (= R7 intent): 512 blocks (XCD band swizzle), block = 512 thr
// (8 waves) = 16x16 px x 128 n. Wave = 64 px x 64 n (4 acc). A-halo (20x20,
// kh-split 64ch) in LDS (51 KB); B direct from global — per-s slab is 16 KB,
// L1-resident, shared by 16 waves/CU; NO barriers in the s-loop so the
// compiler software-pipelines B loads across s. 4 waves/SIMD. Fused BN stats;
// nontemporal planar output.
__global__ __launch_bounds__(512, 4) void gconv_mfma_k(const __hip_bfloat16* __restrict__ nh,
                                                       const __hip_bfloat16* __restrict__ Bgh,
                                                       float* __restrict__ out,
                                                       float* __restrict__ stats) {
    __shared__ short As[8 * 400 * 8];   // 51200 B: [kc 0..7][px_l 0..399][8 shorts]
    __shared__ float sred[32];
    const short* nhwc = (const short*)nh;
    const short* Bg = (const short*)Bgh;
    int bid = blockIdx.x;
    int xcd = bid & 7, q = bid >> 3;
    int b = xcd >> 2, band = xcd & 3;
    int tx0 = (q & 15) << 4;
    int ty0 = (band << 6) + ((q >> 4) << 4);
    int tid = threadIdx.x;
    if (tid < 32) sred[tid] = 0.f;
    int lane = tid & 63;
    int pxg = (tid >> 6) & 3, nhalf = tid >> 8;
    int l31 = lane & 31, half = lane >> 5, lx = lane & 15, yy = l31 >> 4;
    float16 acc[4];
#pragma unroll
    for (int i = 0; i < 4; i++) acc[i] = (float16)0.f;
    const size_t bbase = (size_t)b * HW;
    int yl0 = (pxg << 2) + yy + 2;   // local y of a0 rows (pre-dy); a1 = +2
    int xl0 = lx + 2;
    const int nb = nhalf << 6;

    for (int kh = 0; kh < 2; kh++) {
        __syncthreads();   // As reuse guard (and sred init at kh=0)
        for (int i = tid; i < 3200; i += 512) {
            int kc = i / 400, p = i - kc * 400;
            int yl = p / 20, xl = p - yl * 20;
            int gy = mirror(ty0 - 2 + yl);
            int gx = mirror(tx0 - 2 + xl);
            *(short8*)&As[(kc * 400 + p) * 8] =
                *(const short8*)(nhwc + (bbase + gy * WID + gx) * NHWC_STRIDE + kh * 64 + kc * 8);
        }
        __syncthreads();
        const short* bkh = Bg + kh * 64 + half * 8;
        for (int s = 0; s < 25; s++) {
            int dy = s / 5 - 2, dx = s % 5 - 2;
            int pxa = (yl0 + dy) * 20 + xl0 + dx;
            const short* brow = bkh + (size_t)(s * 128 + nb + l31) * 128;
#pragma unroll
            for (int ks = 0; ks < 4; ks++) {
                int kc = ks * 2 + half;
                short8 a0 = *(const short8*)&As[(kc * 400 + pxa) * 8];
                short8 a1 = *(const short8*)&As[(kc * 400 + pxa + 40) * 8];
#pragma unroll
                for (int nt = 0; nt < 2; nt++) {
                    short8 bb = *(const short8*)(brow + nt * 32 * 128 + ks * 16);
                    acc[nt]     = __builtin_amdgcn_mfma_f32_32x32x16_bf16(a0, bb, acc[nt], 0, 0, 0);
                    acc[2 + nt] = __builtin_amdgcn_mfma_f32_32x32x16_bf16(a1, bb, acc[2 + nt], 0, 0, 0);
                }
            }
        }
    }

    const size_t outb = (size_t)b * PLANE_B;
#pragma unroll
    for (int g = 0; g < 2; g++) {
        int ybase = ty0 + (pxg << 2) + g * 2;
#pragma unroll
        for (int nt = 0; nt < 2; nt++) {
            int n = nb + nt * 32 + l31;
            float* plane = out + outb + (size_t)n * HW;
#pragma unroll
            for (int r4 = 0; r4 < 4; r4++) {
                int base = 8 * r4 + 4 * half;
                float4v v;
                v[0] = acc[g * 2 + nt][r4 * 4 + 0];
                v[1] = acc[g * 2 + nt][r4 * 4 + 1];
                v[2] = acc[g * 2 + nt][r4 * 4 + 2];
                v[3] = acc[g * 2 + nt][r4 * 4 + 3];
                __builtin_nontemporal_store(v,
                    (float4v*)(plane + (size_t)(ybase + (base >> 4)) * WID + tx0 + (base & 15)));
            }
        }
    }
    // BN partial sums (4-acc variant): channel c = n>>3 = nhalf*8 + nt*4 + (l31>>3)
#pragma unroll
    for (int nt = 0; nt < 2; nt++) {
        float sv = 0.f, s2v = 0.f;
#pragma unroll
        for (int g = 0; g < 2; g++)
#pragma unroll
            for (int r = 0; r < 16; r++) {
                float v = acc[g * 2 + nt][r];
                sv += v;
                s2v += v * v;
            }
#pragma unroll
        for (int off = 1; off <= 4; off <<= 1) {
            sv += __shfl_xor(sv, off);
            s2v += __shfl_xor(s2v, off);
        }
        sv += __shfl_xor(sv, 32);
        s2v += __shfl_xor(s2v, 32);
        if ((lane & 39) == 0) {
            int c = (nhalf << 3) + (nt << 2) + (l31 >> 3);
            atomicAdd(&sred[c], sv);
            atomicAdd(&sred[16 + c], s2v);
        }
    }
    __syncthreads();
    if (tid < 16) {
        atomicAdd(&stats[tid * 2], sred[tid]);
        atomicAdd(&stats[tid * 2 + 1], sred[16 + tid]);
    }
}

// 1x1 gconv GEMM: K=128 straight from NHWC; fused BN stats.
__global__ __launch_bounds__(256, 2) void conv1x1_gemm_k(const __hip_bfloat16* __restrict__ nh,
                                                         const __hip_bfloat16* __restrict__ B1h,
                                                         float* __restrict__ out,
                                                         float* __restrict__ stats) {
    __shared__ float sred[32];
    const short* nhwc = (const short*)nh;
    const short* B1 = (const short*)B1h;
    int tid = threadIdx.x;
    if (tid < 32) sred[tid] = 0.f;
    __syncthreads();
    int b = blockIdx.y;
    int wave = tid >> 6, lane = tid & 63;
    int l31 = lane & 31, half = lane >> 5;
    int p0 = blockIdx.x * 256 + wave * 64;
    float16 acc[8];
#pragma unroll
    for (int i = 0; i < 8; i++) acc[i] = (float16)0.f;
    const short* a0p = nhwc + ((size_t)b * HW + p0 + l31) * NHWC_STRIDE + half * 8;
    const short* a1p = a0p + 32 * NHWC_STRIDE;
    const short* bp  = B1 + (size_t)l31 * 128 + half * 8;
#pragma unroll
    for (int ks = 0; ks < 8; ks++) {
        short8 a0 = *(const short8*)(a0p + ks * 16);
        short8 a1 = *(const short8*)(a1p + ks * 16);
#pragma unroll
        for (int nt = 0; nt < 4; nt++) {
            short8 bb = *(const short8*)(bp + nt * 32 * 128 + ks * 16);
            acc[nt]     = __builtin_amdgcn_mfma_f32_32x32x16_bf16(a0, bb, acc[nt], 0, 0, 0);
            acc[4 + nt] = __builtin_amdgcn_mfma_f32_32x32x16_bf16(a1, bb, acc[4 + nt], 0, 0, 0);
        }
    }
    float* outb = out + (size_t)b * PLANE_B;
#pragma unroll
    for (int g = 0; g < 2; g++)
#pragma unroll
        for (int nt = 0; nt < 4; nt++) {
            int n = nt * 32 + l31;
#pragma unroll
            for (int r4 = 0; r4 < 4; r4++) {
                int base = 8 * r4 + 4 * half;
                float4v v;
                v[0] = acc[g * 4 + nt][r4 * 4 + 0];
                v[1] = acc[g * 4 + nt][r4 * 4 + 1];
                v[2] = acc[g * 4 + nt][r4 * 4 + 2];
                v[3] = acc[g * 4 + nt][r4 * 4 + 3];
                __builtin_nontemporal_store(v,
                    (float4v*)(outb + (size_t)n * HW + p0 + g * 32 + base));
            }
        }
    stats_reduce8(acc, lane, l31, sred);
    __syncthreads();
    if (tid < 16) {
        atomicAdd(&stats[tid * 2], sred[tid]);
        atomicAdd(&stats[tid * 2 + 1], sred[16 + tid]);
    }
}

// ---- fused BN-finalize + BN+ReLU + planar->NHWC(bf16, padded) repack ----
__global__ void repack_k(const float* __restrict__ planar, const float* __restrict__ stats,
                         const float* __restrict__ g, const float* __restrict__ beta,
                         __hip_bfloat16* __restrict__ nhwc) {
    __shared__ __hip_bfloat16 ls[128 * NHWC_STRIDE];
    __shared__ float ssl[32];
    if (threadIdx.x < 16) {
        int c = threadIdx.x;
        float mean = stats[c * 2] / BN_N;
        float var = stats[c * 2 + 1] / BN_N - mean * mean;
        float sc = g[c] * rsqrtf(var + 1e-5f);
        ssl[c * 2] = sc;
        ssl[c * 2 + 1] = beta[c] - mean * sc;
    }
    int b = blockIdx.y;
    int px0 = blockIdx.x * 128;
    for (int i = threadIdx.x; i < 128 * 8; i += 256)
        ls[(i >> 3) * NHWC_STRIDE + 128 + (i & 7)] = __float2bfloat16(0.f);
    __syncthreads();
    int px = threadIdx.x & 127;
    int choff = threadIdx.x >> 7;
    const float* pb = planar + (size_t)b * PLANE_B + px0 + px;
    for (int chb = 0; chb < 64; chb++) {
        int ch = chb * 2 + choff;
        int c = ch >> 3;
        float v = pb[(size_t)ch * HW];
        v = v * ssl[c * 2] + ssl[c * 2 + 1];
        v = v > 0.f ? v : 0.f;
        ls[px * NHWC_STRIDE + ch] = __float2bfloat16(v);
    }
    __syncthreads();
    short* outp = (short*)nhwc + ((size_t)b * HW + px0) * NHWC_STRIDE;
    const short* lsp = (const short*)ls;
    for (int i = threadIdx.x; i < 128 * 17; i += 256) {
        int p = i / 17, seg = i % 17;
        *(short8*)(outp + (size_t)p * NHWC_STRIDE + seg * 8) =
            *(const short8*)(lsp + p * NHWC_STRIDE + seg * 8);
    }
}

// ---- BN-finalize + BN+ReLU on conv4, max over m, final 1x1 + sigmoid ----
__global__ void final_k(const float* __restrict__ in, const float* __restrict__ stats,
                        const float* __restrict__ g, const float* __restrict__ beta,
                        const float* __restrict__ fw, void* __restrict__ out,
                        const int* __restrict__ flag) {
    __shared__ float ssl[32];
    if (threadIdx.x < 16) {
        int c = threadIdx.x;
        float mean = stats[c * 2] / BN_N;
        float var = stats[c * 2 + 1] / BN_N - mean * mean;
        float sc = g[c] * rsqrtf(var + 1e-5f);
        ssl[c * 2] = sc;
        ssl[c * 2 + 1] = beta[c] - mean * sc;
    }
    __syncthreads();
    int i = blockIdx.x * blockDim.x + threadIdx.x;
    int b = i >> 16, pix = i & 65535;
    float acc = 0.f;
#pragma unroll
    for (int co = 0; co < 16; co++) {
        float sc = ssl[co * 2], sh = ssl[co * 2 + 1];
        float mx = 0.f;
        const float* p = in + (size_t)b * PLANE_B + (size_t)co * PLANE_C + pix;
#pragma unroll
        for (int m = 0; m < 8; m++) mx = fmaxf(mx, p[m * HW] * sc + sh);
        acc = fmaf(fw[co], mx, acc);
    }
    float r = 1.f / (1.f + expf(-acc));
    if (*flag)
        ((__hip_bfloat16*)out)[i] = __float2bfloat16(r);
    else
        ((float*)out)[i] = r;
}

extern "C" void kernel_launch(void* const* d_in, const int* in_sizes, int n_in,
                              void* d_out, int out_size, void* d_ws, size_t ws_size,
                              hipStream_t stream) {
    float* ws = (float*)d_ws;
    float* planar = ws;                                        // 16,777,216 f
    __hip_bfloat16* nhwc = (__hip_bfloat16*)(ws + 16777216);   // 17,825,792 bf16
    __hip_bfloat16* Alift = (__hip_bfloat16*)(ws + 25690112);  // 10,485,760 bf16
    __hip_bfloat16* Bg    = (__hip_bfloat16*)(ws + 30932992);  // 409,600 bf16
    __hip_bfloat16* Blift = (__hip_bfloat16*)(ws + 31137792);  // 20,480 bf16
    __hip_bfloat16* B1    = (__hip_bfloat16*)(ws + 31148032);  // 16,384 bf16
    // contiguous converted-input region (CVT_TOTAL = 551,392 floats)
    float* xF  = ws + 31156224;        // 393216
    float* lwF = xF + 393216;          // 2352
    float* w1F = lwF + 2352;           // 51200
    float* w2F = w1F + 51200;          // 51200
    float* w3F = w2F + 51200;          // 51200
    float* w4F = w3F + 51200;          // 2048
    float* fwF = w4F + 2048;           // 16
    float* gbF = fwF + 16;             // 160 = g0,b0,g1,b1,...,g4,b4
    float* stats = gbF + 160;          // 32
    int*   flag  = (int*)(stats + 64);

    detect_k<<<1, 256, 0, stream>>>(d_in[0], flag);
    cvt_all_k<<<(CVT_TOTAL + 511) / 512, 512, 0, stream>>>(
        d_in[0], d_in[1], d_in[2], d_in[3], d_in[4], d_in[5], d_in[6], d_in[7], d_in[8],
        d_in[9], d_in[10], d_in[11], d_in[12], d_in[13], d_in[14], d_in[15], d_in[16],
        xF, flag);

    // ---- lift: pack B (zeroes stats), per-batch im2col + GEMM (stats fused) ----
    pack_blift_k<<<(128 * 160 + 255) / 256, 256, 0, stream>>>(lwF, Blift, stats);
    for (int b = 0; b < 2; b++) {
        im2col_lift_k<<<(HW * 160 + 255) / 256, 256, 0, stream>>>(xF + (size_t)b * 3 * HW, Alift);
        lift_gemm_k<<<256, 256, 0, stream>>>(Alift, Blift, planar + (size_t)b * PLANE_B, stats);
    }
    repack_k<<<dim3(512, 2), 256, 0, stream>>>(planar, stats, gbF + 0, gbF + 16, nhwc);

    // ---- gconv 1..3 ----
    float* wlist[3] = {w1F, w2F, w3F};
    for (int l = 0; l < 3; l++) {
        pack_bg_k<<<(25 * 128 * 128 + 255) / 256, 256, 0, stream>>>(wlist[l], Bg, stats);
        gconv_mfma_k<<<512, 512, 0, stream>>>(nhwc, Bg, planar, stats);
        repack_k<<<dim3(512, 2), 256, 0, stream>>>(planar, stats,
                                                   gbF + 32 * (l + 1), gbF + 32 * (l + 1) + 16, nhwc);
    }

    // ---- conv4 (1x1, stats fused; BN/ReLU applied in final_k) ----
    pack_b1_k<<<(128 * 128 + 255) / 256, 256, 0, stream>>>(w4F, B1, stats);
    conv1x1_gemm_k<<<dim3(256, 2), 256, 0, stream>>>(nhwc, B1, planar, stats);

    // ---- max-project + final 1x1 + sigmoid ----
    final_k<<<(2 * HW) / 256, 256, 0, stream>>>(planar, stats, gbF + 128, gbF + 144,
                                                fwF, d_out, flag);
}

// Round 9
// 633.989 us; speedup vs baseline: 1.7679x; 1.6250x over previous
//
#include <hip/hip_runtime.h>
#include <hip/hip_bf16.h>
#include <math.h>

// Activations: planar fp32 [B=2][plane=128][256*256] in ws; between layers NHWC bf16
// [B][256*256][136] (ch = ci*8 + o, padded 128->136 for 16B-aligned rows).
#define HW 65536
#define WID 256
#define NOR 8
#define PLANE_C (NOR * HW)          // 524288
#define PLANE_B (16 * NOR * HW)     // 8388608
#define NELEM (2 * PLANE_B)         // 16777216
#define BN_N 1048576.0f
#define NHWC_STRIDE 136             // shorts per pixel (128 real + 8 pad)

typedef __attribute__((ext_vector_type(8)))  short  short8;
typedef __attribute__((ext_vector_type(16))) float  float16;
typedef __attribute__((ext_vector_type(4)))  float  float4v;

// ---- runtime dtype detection (bf16 vs fp32 storage), validated in R2/R3 ----
__global__ void detect_k(const void* __restrict__ x, int* __restrict__ flag) {
    __shared__ int bad;
    if (threadIdx.x == 0) bad = 0;
    __syncthreads();
    const __hip_bfloat16* p = (const __hip_bfloat16*)x;
    for (int i = threadIdx.x; i < 4096; i += 256) {
        float v = __bfloat162float(p[i]);
        if (!(fabsf(v) < 1e4f)) atomicOr(&bad, 1);
    }
    __syncthreads();
    if (threadIdx.x == 0) *flag = bad ? 0 : 1;
}

// ---- single-dispatch conversion of all 17 inputs into contiguous fp32 region ----
// x 393216 | lw 2352 | w1 51200 | w2 51200 | w3 51200 | w4 2048 | fw 16 | 10x16
#define CVT_TOTAL 551392
__global__ void cvt_all_k(const void* p0, const void* p1, const void* p2, const void* p3,
                          const void* p4, const void* p5, const void* p6, const void* p7,
                          const void* p8, const void* p9, const void* p10, const void* p11,
                          const void* p12, const void* p13, const void* p14, const void* p15,
                          const void* p16, float* __restrict__ dst, const int* __restrict__ flag) {
    int i = blockIdx.x * 512 + threadIdx.x;
    if (i >= CVT_TOTAL) return;
    const void* src; int off;
    if      (i < 393216) { src = p0;  off = 0; }
    else if (i < 395568) { src = p1;  off = 393216; }
    else if (i < 446768) { src = p2;  off = 395568; }
    else if (i < 497968) { src = p3;  off = 446768; }
    else if (i < 549168) { src = p4;  off = 497968; }
    else if (i < 551216) { src = p5;  off = 549168; }
    else if (i < 551232) { src = p6;  off = 551216; }
    else if (i < 551248) { src = p7;  off = 551232; }
    else if (i < 551264) { src = p8;  off = 551248; }
    else if (i < 551280) { src = p9;  off = 551264; }
    else if (i < 551296) { src = p10; off = 551280; }
    else if (i < 551312) { src = p11; off = 551296; }
    else if (i < 551328) { src = p12; off = 551312; }
    else if (i < 551344) { src = p13; off = 551328; }
    else if (i < 551360) { src = p14; off = 551344; }
    else if (i < 551376) { src = p15; off = 551360; }
    else                 { src = p16; off = 551376; }
    int j = i - off;
    dst[i] = (*flag) ? __bfloat162float(((const __hip_bfloat16*)src)[j])
                     : ((const float*)src)[j];
}

// ---- bilinear kernel rotation (bit-identical to R2..R8, which passed) ----
__device__ float rot_sample(const float* __restrict__ W, int k, float theta, int i, int j) {
    float c = 0.5f * (float)(k - 1);
    float ys = (float)i - c, xs = (float)j - c;
    float cs = cosf(theta), sn = sinf(theta);
    float sy = cs * ys - sn * xs + c;
    float sx = sn * ys + cs * xs + c;
    float fy = floorf(sy), fx = floorf(sx);
    int y0 = (int)fy, x0 = (int)fx;
    float wy = sy - fy, wx = sx - fx;
    float v00 = (y0 >= 0 && y0 < k && x0 >= 0 && x0 < k)                 ? W[y0 * k + x0]           : 0.f;
    float v01 = (y0 >= 0 && y0 < k && x0 + 1 >= 0 && x0 + 1 < k)         ? W[y0 * k + x0 + 1]       : 0.f;
    float v10 = (y0 + 1 >= 0 && y0 + 1 < k && x0 >= 0 && x0 < k)         ? W[(y0 + 1) * k + x0]     : 0.f;
    float v11 = (y0 + 1 >= 0 && y0 + 1 < k && x0 + 1 >= 0 && x0 + 1 < k) ? W[(y0 + 1) * k + x0 + 1] : 0.f;
    return v00 * (1 - wy) * (1 - wx) + v01 * (1 - wy) * wx
         + v10 * wy * (1 - wx) + v11 * wy * wx;
}

__device__ __forceinline__ float theta_of(int m) {
    return (6.2831855f * (float)m) / 8.0f;
}

__device__ __forceinline__ int mirror(int i) {
    i = i < 0 ? -i : i;
    return i >= WID ? (2 * WID - 2 - i) : i;
}

// ---- weight packs (stats-zero folded in) ----
__global__ void pack_blift_k(const float* __restrict__ lw, __hip_bfloat16* __restrict__ B,
                             float* __restrict__ stats) {
    int idx = blockIdx.x * 256 + threadIdx.x;
    if (idx < 32) stats[idx] = 0.f;
    if (idx >= 128 * 160) return;
    int n = idx / 160, k = idx % 160;
    float v = 0.f;
    if (k < 147) {
        int c = n >> 3, o = n & 7;
        int ci = k / 49, s = k % 49;
        v = rot_sample(lw + (c * 3 + ci) * 49, 7, theta_of(o), s / 7, s % 7);
    }
    B[idx] = __float2bfloat16(v);
}

// gconv pack, R9 layout for 16x16x32 B-frags:
// Bg[q(4)][s(25)][kc4(4)][n(128)][j(8)]  with ch = q*32 + kc4*8 + j
__global__ void pack_bg_k(const float* __restrict__ w, __hip_bfloat16* __restrict__ Bg,
                          float* __restrict__ stats) {
    int idx = blockIdx.x * 256 + threadIdx.x;
    if (idx < 32) stats[idx] = 0.f;
    if (idx >= 409600) return;
    int j = idx & 7;
    int n = (idx >> 3) & 127;
    int kc4 = (idx >> 10) & 3;
    int sq = idx >> 12;              // 0..99
    int s = sq % 25, q = sq / 25;
    int ch = q * 32 + kc4 * 8 + j;
    int co = n >> 3, m = n & 7, ci = ch >> 3, o = ch & 7;
    int oo = (o - m + 8) & 7;
    float v = rot_sample(w + ((co * 16 + ci) * 8 + oo) * 25, 5, theta_of(m), s / 5, s % 5);
    Bg[idx] = __float2bfloat16(v);
}

__global__ void pack_b1_k(const float* __restrict__ w4, __hip_bfloat16* __restrict__ B1,
                          float* __restrict__ stats) {
    int idx = blockIdx.x * 256 + threadIdx.x;
    if (idx < 32) stats[idx] = 0.f;
    if (idx >= 128 * 128) return;
    int n = idx >> 7, ch = idx & 127;
    int co = n >> 3, m = n & 7, ci = ch >> 3, o = ch & 7;
    B1[idx] = __float2bfloat16(w4[(co * 16 + ci) * 8 + ((o - m + 8) & 7)]);
}

// ---- lift im2col (one batch): A[px][160] bf16, k = ci*49 + dy*7 + dx ----
__global__ void im2col_lift_k(const float* __restrict__ xb, __hip_bfloat16* __restrict__ A) {
    int idx = blockIdx.x * 256 + threadIdx.x;
    if (idx >= HW * 160) return;
    int px = idx / 160, k = idx % 160;
    float v = 0.f;
    if (k < 147) {
        int ci = k / 49, s = k % 49;
        int gy = mirror((px >> 8) + s / 7 - 3);
        int gx = mirror((px & 255) + s % 7 - 3);
        v = xb[ci * HW + gy * WID + gx];
    }
    A[idx] = __float2bfloat16(v);
}

// ---- MFMA fragment conventions:
// 32x32x16 (verified R3..R8): A lane: A[m=lane&31][k=(lane>>5)*8+j]; C/D col=lane&31,
//   row=(reg&3)+8*(reg>>2)+4*(lane>>5).
// 16x16x32 (guide m89, attention notes): A lane: A[m=lane&15][k=(lane>>4)*8+j];
//   B lane: B[k=(lane>>4)*8+j][n=lane&15]; C/D col=lane&15, row=(lane>>4)*4+reg.

// BN partial-sum reduction (8-acc 32x32 variant) into sred[32].
__device__ __forceinline__ void stats_reduce8(const float16* acc, int lane, int l31,
                                              float* sred) {
#pragma unroll
    for (int nt = 0; nt < 4; nt++) {
        float sv = 0.f, s2v = 0.f;
#pragma unroll
        for (int g = 0; g < 2; g++)
#pragma unroll
            for (int r = 0; r < 16; r++) {
                float v = acc[g * 4 + nt][r];
                sv += v;
                s2v += v * v;
            }
#pragma unroll
        for (int off = 1; off <= 4; off <<= 1) {
            sv += __shfl_xor(sv, off);
            s2v += __shfl_xor(s2v, off);
        }
        sv += __shfl_xor(sv, 32);
        s2v += __shfl_xor(s2v, 32);
        if ((lane & 39) == 0) {
            int c = nt * 4 + (l31 >> 3);
            atomicAdd(&sred[c], sv);
            atomicAdd(&sred[16 + c], s2v);
        }
    }
}

// lift GEMM: M=65536 (one b), K=160 (10 ksteps), N=128. out pre-offset by b.
__global__ __launch_bounds__(256, 2) void lift_gemm_k(const __hip_bfloat16* __restrict__ Ah,
                                                      const __hip_bfloat16* __restrict__ Bh,
                                                      float* __restrict__ out,
                                                      float* __restrict__ stats) {
    __shared__ float sred[32];
    const short* A = (const short*)Ah;
    const short* B = (const short*)Bh;
    int tid = threadIdx.x;
    if (tid < 32) sred[tid] = 0.f;
    __syncthreads();
    int wave = tid >> 6, lane = tid & 63;
    int l31 = lane & 31, half = lane >> 5;
    int p0 = blockIdx.x * 256 + wave * 64;
    float16 acc[8];
#pragma unroll
    for (int i = 0; i < 8; i++) acc[i] = (float16)0.f;
    const short* a0p = A + (size_t)(p0 + l31) * 160 + half * 8;
    const short* a1p = a0p + 32 * 160;
    const short* bp  = B + (size_t)l31 * 160 + half * 8;
#pragma unroll
    for (int ks = 0; ks < 10; ks++) {
        short8 a0 = *(const short8*)(a0p + ks * 16);
        short8 a1 = *(const short8*)(a1p + ks * 16);
#pragma unroll
        for (int nt = 0; nt < 4; nt++) {
            short8 bb = *(const short8*)(bp + nt * 32 * 160 + ks * 16);
            acc[nt]     = __builtin_amdgcn_mfma_f32_32x32x16_bf16(a0, bb, acc[nt], 0, 0, 0);
            acc[4 + nt] = __builtin_amdgcn_mfma_f32_32x32x16_bf16(a1, bb, acc[4 + nt], 0, 0, 0);
        }
    }
#pragma unroll
    for (int g = 0; g < 2; g++)
#pragma unroll
        for (int nt = 0; nt < 4; nt++) {
            int n = nt * 32 + l31;
#pragma unroll
            for (int r4 = 0; r4 < 4; r4++) {
                int base = 8 * r4 + 4 * half;
                float4v v;
                v[0] = acc[g * 4 + nt][r4 * 4 + 0];
                v[1] = acc[g * 4 + nt][r4 * 4 + 1];
                v[2] = acc[g * 4 + nt][r4 * 4 + 2];
                v[3] = acc[g * 4 + nt][r4 * 4 + 3];
                *(float4v*)(out + (size_t)n * HW + p0 + g * 32 + base) = v;
            }
        }
    stats_reduce8(acc, lane, l31, sred);
    __syncthreads();
    if (tid < 16) {
        atomicAdd(&stats[tid * 2], sred[tid]);
        atomicAdd(&stats[tid * 2 + 1], sred[16 + tid]);
    }
}

// gconv GEMM R9: 1024 blocks (XCD band swizzle), block = 256 thr (4 waves) =
// 16x16 px x 64 n-half. Wave = 64 px (4 rows of 16) x 64 n, 16x16x32 MFMA,
// 4x4 acc tile (16 accs = 64 AGPR) -> 0.5 operand-reads per MFMA (2x better
// than R8). A-halo per kh-QUARTER (32 ch) in LDS, padded row-stride 21 /
// kc-stride 441 units (4-bank stagger, kills R8's 6.5M conflicts). B direct
// from global (L1-hot 4KB slabs). launch_bounds(256,3) leaves ~106 VGPRs for
// the compiler to pipeline B loads across s (R8's 64-VGPR starvation fix).
// Barrier-free s-loop; 8 barriers total. Plain stores (NT caused write
// amplification 77->148 MB). Fused BN stats.
__global__ __launch_bounds__(256, 3) void gconv_mfma_k(const __hip_bfloat16* __restrict__ nh,
                                                       const __hip_bfloat16* __restrict__ Bgh,
                                                       float* __restrict__ out,
                                                       float* __restrict__ stats) {
    __shared__ short As[4 * 441 * 8];   // 28224 B, [kc 0..3][yl*21+xl] x 8 shorts
    __shared__ float sred[32];
    const short* nhwc = (const short*)nh;
    const short* Bg = (const short*)Bgh;
    int bid = blockIdx.x;
    int xcd = bid & 7;
    int q2 = bid >> 3;              // 0..127
    int nhalf = q2 & 1;
    int qt = q2 >> 1;               // 0..63 tile-in-band
    int b = xcd >> 2, band = xcd & 3;
    int tx0 = (qt & 15) << 4;
    int ty0 = (band << 6) + ((qt >> 4) << 4);
    int tid = threadIdx.x;
    if (tid < 32) sred[tid] = 0.f;
    int w = tid >> 6, lane = tid & 63;
    int l15 = lane & 15, l4 = lane >> 4;
    float4v acc[16];
#pragma unroll
    for (int i = 0; i < 16; i++) acc[i] = (float4v)0.f;
    const size_t bbase = (size_t)b * HW;
    const int nb = nhalf << 6;

    for (int q = 0; q < 4; q++) {
        __syncthreads();   // As reuse guard (and sred init at q=0)
        for (int i = tid; i < 1600; i += 256) {
            int kc = i / 400, p = i - kc * 400;
            int yl = p / 20, xl = p - yl * 20;
            int gy = mirror(ty0 - 2 + yl);
            int gx = mirror(tx0 - 2 + xl);
            *(short8*)&As[(kc * 441 + yl * 21 + xl) * 8] =
                *(const short8*)(nhwc + (bbase + gy * WID + gx) * NHWC_STRIDE + q * 32 + kc * 8);
        }
        __syncthreads();
        for (int s = 0; s < 25; s++) {
            int dy = s / 5 - 2, dx = s % 5 - 2;
            int abase = l4 * 441 + ((w << 2) + 2 + dy) * 21 + (l15 + 2 + dx);
            const short* brow = Bg + ((size_t)(((q * 25 + s) << 2) + l4) * 128 + nb + l15) * 8;
            short8 a0 = *(const short8*)&As[abase * 8];
            short8 a1 = *(const short8*)&As[(abase + 21) * 8];
            short8 a2 = *(const short8*)&As[(abase + 42) * 8];
            short8 a3 = *(const short8*)&As[(abase + 63) * 8];
#pragma unroll
            for (int nt = 0; nt < 4; nt++) {
                short8 bb = *(const short8*)(brow + nt * 128);
                acc[nt]      = __builtin_amdgcn_mfma_f32_16x16x32_bf16(a0, bb, acc[nt], 0, 0, 0);
                acc[4 + nt]  = __builtin_amdgcn_mfma_f32_16x16x32_bf16(a1, bb, acc[4 + nt], 0, 0, 0);
                acc[8 + nt]  = __builtin_amdgcn_mfma_f32_16x16x32_bf16(a2, bb, acc[8 + nt], 0, 0, 0);
                acc[12 + nt] = __builtin_amdgcn_mfma_f32_16x16x32_bf16(a3, bb, acc[12 + nt], 0, 0, 0);
            }
        }
    }

    // C/D (16x16): lane holds col n = nb + nt*16 + l15; rows x = tx0 + l4*4 + reg
    // (contiguous float4 in x); y = ty0 + w*4 + ag.
    const size_t outb = (size_t)b * PLANE_B;
#pragma unroll
    for (int ag = 0; ag < 4; ag++) {
        int y = ty0 + (w << 2) + ag;
#pragma unroll
        for (int nt = 0; nt < 4; nt++) {
            int n = nb + nt * 16 + l15;
            *(float4v*)(out + outb + (size_t)n * HW + (size_t)y * WID + tx0 + (l4 << 2))
                = acc[ag * 4 + nt];
        }
    }
    // BN partial sums: channel c = n>>3 = nhalf*8 + nt*2 + (l15>>3)
#pragma unroll
    for (int nt = 0; nt < 4; nt++) {
        float sv = 0.f, s2v = 0.f;
#pragma unroll
        for (int ag = 0; ag < 4; ag++)
#pragma unroll
            for (int r = 0; r < 4; r++) {
                float v = acc[ag * 4 + nt][r];
                sv += v;
                s2v += v * v;
            }
#pragma unroll
        for (int off = 1; off <= 4; off <<= 1) {
            sv += __shfl_xor(sv, off);
            s2v += __shfl_xor(s2v, off);
        }
        sv += __shfl_xor(sv, 16);
        s2v += __shfl_xor(s2v, 16);
        sv += __shfl_xor(sv, 32);
        s2v += __shfl_xor(s2v, 32);
        if ((lane & 7) == 0 && l4 == 0) {   // lanes 0, 8
            int c = (nhalf << 3) + (nt << 1) + (l15 >> 3);
            atomicAdd(&sred[c], sv);
            atomicAdd(&sred[16 + c], s2v);
        }
    }
    __syncthreads();
    if (tid < 16) {
        atomicAdd(&stats[tid * 2], sred[tid]);
        atomicAdd(&stats[tid * 2 + 1], sred[16 + tid]);
    }
}

// 1x1 gconv GEMM: K=128 straight from NHWC; fused BN stats.
__global__ __launch_bounds__(256, 2) void conv1x1_gemm_k(const __hip_bfloat16* __restrict__ nh,
                                                         const __hip_bfloat16* __restrict__ B1h,
                                                         float* __restrict__ out,
                                                         float* __restrict__ stats) {
    __shared__ float sred[32];
    const short* nhwc = (const short*)nh;
    const short* B1 = (const short*)B1h;
    int tid = threadIdx.x;
    if (tid < 32) sred[tid] = 0.f;
    __syncthreads();
    int b = blockIdx.y;
    int wave = tid >> 6, lane = tid & 63;
    int l31 = lane & 31, half = lane >> 5;
    int p0 = blockIdx.x * 256 + wave * 64;
    float16 acc[8];
#pragma unroll
    for (int i = 0; i < 8; i++) acc[i] = (float16)0.f;
    const short* a0p = nhwc + ((size_t)b * HW + p0 + l31) * NHWC_STRIDE + half * 8;
    const short* a1p = a0p + 32 * NHWC_STRIDE;
    const short* bp  = B1 + (size_t)l31 * 128 + half * 8;
#pragma unroll
    for (int ks = 0; ks < 8; ks++) {
        short8 a0 = *(const short8*)(a0p + ks * 16);
        short8 a1 = *(const short8*)(a1p + ks * 16);
#pragma unroll
        for (int nt = 0; nt < 4; nt++) {
            short8 bb = *(const short8*)(bp + nt * 32 * 128 + ks * 16);
            acc[nt]     = __builtin_amdgcn_mfma_f32_32x32x16_bf16(a0, bb, acc[nt], 0, 0, 0);
            acc[4 + nt] = __builtin_amdgcn_mfma_f32_32x32x16_bf16(a1, bb, acc[4 + nt], 0, 0, 0);
        }
    }
    float* outb = out + (size_t)b * PLANE_B;
#pragma unroll
    for (int g = 0; g < 2; g++)
#pragma unroll
        for (int nt = 0; nt < 4; nt++) {
            int n = nt * 32 + l31;
#pragma unroll
            for (int r4 = 0; r4 < 4; r4++) {
                int base = 8 * r4 + 4 * half;
                float4v v;
                v[0] = acc[g * 4 + nt][r4 * 4 + 0];
                v[1] = acc[g * 4 + nt][r4 * 4 + 1];
                v[2] = acc[g * 4 + nt][r4 * 4 + 2];
                v[3] = acc[g * 4 + nt][r4 * 4 + 3];
                *(float4v*)(outb + (size_t)n * HW + p0 + g * 32 + base) = v;
            }
        }
    stats_reduce8(acc, lane, l31, sred);
    __syncthreads();
    if (tid < 16) {
        atomicAdd(&stats[tid * 2], sred[tid]);
        atomicAdd(&stats[tid * 2 + 1], sred[16 + tid]);
    }
}

// ---- fused BN-finalize + BN+ReLU + planar->NHWC(bf16, padded) repack ----
__global__ void repack_k(const float* __restrict__ planar, const float* __restrict__ stats,
                         const float* __restrict__ g, const float* __restrict__ beta,
                         __hip_bfloat16* __restrict__ nhwc) {
    __shared__ __hip_bfloat16 ls[128 * NHWC_STRIDE];
    __shared__ float ssl[32];
    if (threadIdx.x < 16) {
        int c = threadIdx.x;
        float mean = stats[c * 2] / BN_N;
        float var = stats[c * 2 + 1] / BN_N - mean * mean;
        float sc = g[c] * rsqrtf(var + 1e-5f);
        ssl[c * 2] = sc;
        ssl[c * 2 + 1] = beta[c] - mean * sc;
    }
    int b = blockIdx.y;
    int px0 = blockIdx.x * 128;
    for (int i = threadIdx.x; i < 128 * 8; i += 256)
        ls[(i >> 3) * NHWC_STRIDE + 128 + (i & 7)] = __float2bfloat16(0.f);
    __syncthreads();
    int px = threadIdx.x & 127;
    int choff = threadIdx.x >> 7;
    const float* pb = planar + (size_t)b * PLANE_B + px0 + px;
    for (int chb = 0; chb < 64; chb++) {
        int ch = chb * 2 + choff;
        int c = ch >> 3;
        float v = pb[(size_t)ch * HW];
        v = v * ssl[c * 2] + ssl[c * 2 + 1];
        v = v > 0.f ? v : 0.f;
        ls[px * NHWC_STRIDE + ch] = __float2bfloat16(v);
    }
    __syncthreads();
    short* outp = (short*)nhwc + ((size_t)b * HW + px0) * NHWC_STRIDE;
    const short* lsp = (const short*)ls;
    for (int i = threadIdx.x; i < 128 * 17; i += 256) {
        int p = i / 17, seg = i % 17;
        *(short8*)(outp + (size_t)p * NHWC_STRIDE + seg * 8) =
            *(const short8*)(lsp + p * NHWC_STRIDE + seg * 8);
    }
}

// ---- BN-finalize + BN+ReLU on conv4, max over m, final 1x1 + sigmoid ----
__global__ void final_k(const float* __restrict__ in, const float* __restrict__ stats,
                        const float* __restrict__ g, const float* __restrict__ beta,
                        const float* __restrict__ fw, void* __restrict__ out,
                        const int* __restrict__ flag) {
    __shared__ float ssl[32];
    if (threadIdx.x < 16) {
        int c = threadIdx.x;
        float mean = stats[c * 2] / BN_N;
        float var = stats[c * 2 + 1] / BN_N - mean * mean;
        float sc = g[c] * rsqrtf(var + 1e-5f);
        ssl[c * 2] = sc;
        ssl[c * 2 + 1] = beta[c] - mean * sc;
    }
    __syncthreads();
    int i = blockIdx.x * blockDim.x + threadIdx.x;
    int b = i >> 16, pix = i & 65535;
    float acc = 0.f;
#pragma unroll
    for (int co = 0; co < 16; co++) {
        float sc = ssl[co * 2], sh = ssl[co * 2 + 1];
        float mx = 0.f;
        const float* p = in + (size_t)b * PLANE_B + (size_t)co * PLANE_C + pix;
#pragma unroll
        for (int m = 0; m < 8; m++) mx = fmaxf(mx, p[m * HW] * sc + sh);
        acc = fmaf(fw[co], mx, acc);
    }
    float r = 1.f / (1.f + expf(-acc));
    if (*flag)
        ((__hip_bfloat16*)out)[i] = __float2bfloat16(r);
    else
        ((float*)out)[i] = r;
}

extern "C" void kernel_launch(void* const* d_in, const int* in_sizes, int n_in,
                              void* d_out, int out_size, void* d_ws, size_t ws_size,
                              hipStream_t stream) {
    float* ws = (float*)d_ws;
    float* planar = ws;                                        // 16,777,216 f
    __hip_bfloat16* nhwc = (__hip_bfloat16*)(ws + 16777216);   // 17,825,792 bf16
    __hip_bfloat16* Alift = (__hip_bfloat16*)(ws + 25690112);  // 10,485,760 bf16
    __hip_bfloat16* Bg    = (__hip_bfloat16*)(ws + 30932992);  // 409,600 bf16
    __hip_bfloat16* Blift = (__hip_bfloat16*)(ws + 31137792);  // 20,480 bf16
    __hip_bfloat16* B1    = (__hip_bfloat16*)(ws + 31148032);  // 16,384 bf16
    // contiguous converted-input region (CVT_TOTAL = 551,392 floats)
    float* xF  = ws + 31156224;        // 393216
    float* lwF = xF + 393216;          // 2352
    float* w1F = lwF + 2352;           // 51200
    float* w2F = w1F + 51200;          // 51200
    float* w3F = w2F + 51200;          // 51200
    float* w4F = w3F + 51200;          // 2048
    float* fwF = w4F + 2048;           // 16
    float* gbF = fwF + 16;             // 160 = g0,b0,g1,b1,...,g4,b4
    float* stats = gbF + 160;          // 32
    int*   flag  = (int*)(stats + 64);

    detect_k<<<1, 256, 0, stream>>>(d_in[0], flag);
    cvt_all_k<<<(CVT_TOTAL + 511) / 512, 512, 0, stream>>>(
        d_in[0], d_in[1], d_in[2], d_in[3], d_in[4], d_in[5], d_in[6], d_in[7], d_in[8],
        d_in[9], d_in[10], d_in[11], d_in[12], d_in[13], d_in[14], d_in[15], d_in[16],
        xF, flag);

    // ---- lift: pack B (zeroes stats), per-batch im2col + GEMM (stats fused) ----
    pack_blift_k<<<(128 * 160 + 255) / 256, 256, 0, stream>>>(lwF, Blift, stats);
    for (int b = 0; b < 2; b++) {
        im2col_lift_k<<<(HW * 160 + 255) / 256, 256, 0, stream>>>(xF + (size_t)b * 3 * HW, Alift);
        lift_gemm_k<<<256, 256, 0, stream>>>(Alift, Blift, planar + (size_t)b * PLANE_B, stats);
    }
    repack_k<<<dim3(512, 2), 256, 0, stream>>>(planar, stats, gbF + 0, gbF + 16, nhwc);

    // ---- gconv 1..3 ----
    float* wlist[3] = {w1F, w2F, w3F};
    for (int l = 0; l < 3; l++) {
        pack_bg_k<<<(409600 + 255) / 256, 256, 0, stream>>>(wlist[l], Bg, stats);
        gconv_mfma_k<<<1024, 256, 0, stream>>>(nhwc, Bg, planar, stats);
        repack_k<<<dim3(512, 2), 256, 0, stream>>>(planar, stats,
                                                   gbF + 32 * (l + 1), gbF + 32 * (l + 1) + 16, nhwc);
    }

    // ---- conv4 (1x1, stats fused; BN/ReLU applied in final_k) ----
    pack_b1_k<<<(128 * 128 + 255) / 256, 256, 0, stream>>>(w4F, B1, stats);
    conv1x1_gemm_k<<<dim3(256, 2), 256, 0, stream>>>(nhwc, B1, planar, stats);

    // ---- max-project + final 1x1 + sigmoid ----
    final_k<<<(2 * HW) / 256, 256, 0, stream>>>(planar, stats, gbF + 128, gbF + 144,
                                                fwF, d_out, flag);
}

// Round 10
// 557.902 us; speedup vs baseline: 2.0090x; 1.1364x over previous
//
#include <hip/hip_runtime.h>
#include <hip/hip_bf16.h>
#include <math.h>

// Between layers: NHWC bf16 RAW (pre-BN) [B][256*256][136] (ch=ci*8+o, pad->136).
// BN+ReLU applied during the NEXT layer's staging from fused batch stats.
#define HW 65536
#define WID 256
#define NOR 8
#define PLANE_C (NOR * HW)          // 524288
#define PLANE_B (16 * NOR * HW)     // 8388608
#define BN_N 1048576.0f
#define NHWC_STRIDE 136

typedef __attribute__((ext_vector_type(8)))  short  short8;
typedef __attribute__((ext_vector_type(4)))  short  short4v;
typedef __attribute__((ext_vector_type(16))) float  float16;
typedef __attribute__((ext_vector_type(4)))  float  float4v;

__device__ __forceinline__ float b2f(short s) {
    union { unsigned int u; float f; } c;
    c.u = ((unsigned int)(unsigned short)s) << 16;
    return c.f;
}
__device__ __forceinline__ short f2b(float f) {
    union { __hip_bfloat16 h; short s; } c;
    c.h = __float2bfloat16(f);
    return c.s;
}

// ---- runtime dtype detection (validated R2/R3) ----
__global__ void detect_k(const void* __restrict__ x, int* __restrict__ flag) {
    __shared__ int bad;
    if (threadIdx.x == 0) bad = 0;
    __syncthreads();
    const __hip_bfloat16* p = (const __hip_bfloat16*)x;
    for (int i = threadIdx.x; i < 4096; i += 256) {
        float v = __bfloat162float(p[i]);
        if (!(fabsf(v) < 1e4f)) atomicOr(&bad, 1);
    }
    __syncthreads();
    if (threadIdx.x == 0) *flag = bad ? 0 : 1;
}

// ---- all-inputs conversion (sizes verified R8) ----
#define CVT_TOTAL 551392
__global__ void cvt_all_k(const void* p0, const void* p1, const void* p2, const void* p3,
                          const void* p4, const void* p5, const void* p6, const void* p7,
                          const void* p8, const void* p9, const void* p10, const void* p11,
                          const void* p12, const void* p13, const void* p14, const void* p15,
                          const void* p16, float* __restrict__ dst, const int* __restrict__ flag) {
    int i = blockIdx.x * 512 + threadIdx.x;
    if (i >= CVT_TOTAL) return;
    const void* src; int off;
    if      (i < 393216) { src = p0;  off = 0; }
    else if (i < 395568) { src = p1;  off = 393216; }
    else if (i < 446768) { src = p2;  off = 395568; }
    else if (i < 497968) { src = p3;  off = 446768; }
    else if (i < 549168) { src = p4;  off = 497968; }
    else if (i < 551216) { src = p5;  off = 549168; }
    else if (i < 551232) { src = p6;  off = 551216; }
    else if (i < 551248) { src = p7;  off = 551232; }
    else if (i < 551264) { src = p8;  off = 551248; }
    else if (i < 551280) { src = p9;  off = 551264; }
    else if (i < 551296) { src = p10; off = 551280; }
    else if (i < 551312) { src = p11; off = 551296; }
    else if (i < 551328) { src = p12; off = 551312; }
    else if (i < 551344) { src = p13; off = 551328; }
    else if (i < 551360) { src = p14; off = 551344; }
    else if (i < 551376) { src = p15; off = 551360; }
    else                 { src = p16; off = 551376; }
    int j = i - off;
    dst[i] = (*flag) ? __bfloat162float(((const __hip_bfloat16*)src)[j])
                     : ((const float*)src)[j];
}

// ---- bilinear kernel rotation (bit-identical to R2..R9) ----
__device__ float rot_sample(const float* __restrict__ W, int k, float theta, int i, int j) {
    float c = 0.5f * (float)(k - 1);
    float ys = (float)i - c, xs = (float)j - c;
    float cs = cosf(theta), sn = sinf(theta);
    float sy = cs * ys - sn * xs + c;
    float sx = sn * ys + cs * xs + c;
    float fy = floorf(sy), fx = floorf(sx);
    int y0 = (int)fy, x0 = (int)fx;
    float wy = sy - fy, wx = sx - fx;
    float v00 = (y0 >= 0 && y0 < k && x0 >= 0 && x0 < k)                 ? W[y0 * k + x0]           : 0.f;
    float v01 = (y0 >= 0 && y0 < k && x0 + 1 >= 0 && x0 + 1 < k)         ? W[y0 * k + x0 + 1]       : 0.f;
    float v10 = (y0 + 1 >= 0 && y0 + 1 < k && x0 >= 0 && x0 < k)         ? W[(y0 + 1) * k + x0]     : 0.f;
    float v11 = (y0 + 1 >= 0 && y0 + 1 < k && x0 + 1 >= 0 && x0 + 1 < k) ? W[(y0 + 1) * k + x0 + 1] : 0.f;
    return v00 * (1 - wy) * (1 - wx) + v01 * (1 - wy) * wx
         + v10 * wy * (1 - wx) + v11 * wy * wx;
}

__device__ __forceinline__ float theta_of(int m) {
    return (6.2831855f * (float)m) / 8.0f;
}

__device__ __forceinline__ int mirror(int i) {
    i = i < 0 ? -i : i;
    return i >= WID ? (2 * WID - 2 - i) : i;
}

// ---- weight packs (zero the target layer's stats) ----
__global__ void pack_blift_k(const float* __restrict__ lw, __hip_bfloat16* __restrict__ B,
                             float* __restrict__ stats) {
    int idx = blockIdx.x * 256 + threadIdx.x;
    if (idx < 32) stats[idx] = 0.f;
    if (idx >= 128 * 160) return;
    int n = idx / 160, k = idx % 160;
    float v = 0.f;
    if (k < 147) {
        int c = n >> 3, o = n & 7;
        int ci = k / 49, s = k % 49;
        v = rot_sample(lw + (c * 3 + ci) * 49, 7, theta_of(o), s / 7, s % 7);
    }
    B[idx] = __float2bfloat16(v);
}

// Bg[q(4)][s(25)][kc4(4)][n(128)][j(8)], ch = q*32 + kc4*8 + j  (R9 layout)
__global__ void pack_bg_k(const float* __restrict__ w, __hip_bfloat16* __restrict__ Bg,
                          float* __restrict__ stats) {
    int idx = blockIdx.x * 256 + threadIdx.x;
    if (idx < 32) stats[idx] = 0.f;
    if (idx >= 409600) return;
    int j = idx & 7;
    int n = (idx >> 3) & 127;
    int kc4 = (idx >> 10) & 3;
    int sq = idx >> 12;
    int s = sq % 25, q = sq / 25;
    int ch = q * 32 + kc4 * 8 + j;
    int co = n >> 3, m = n & 7, ci = ch >> 3, o = ch & 7;
    int oo = (o - m + 8) & 7;
    float v = rot_sample(w + ((co * 16 + ci) * 8 + oo) * 25, 5, theta_of(m), s / 5, s % 5);
    Bg[idx] = __float2bfloat16(v);
}

__global__ void pack_b1_k(const float* __restrict__ w4, __hip_bfloat16* __restrict__ B1,
                          float* __restrict__ stats) {
    int idx = blockIdx.x * 256 + threadIdx.x;
    if (idx < 32) stats[idx] = 0.f;
    if (idx >= 128 * 128) return;
    int n = idx >> 7, ch = idx & 127;
    int co = n >> 3, m = n & 7, ci = ch >> 3, o = ch & 7;
    B1[idx] = __float2bfloat16(w4[(co * 16 + ci) * 8 + ((o - m + 8) & 7)]);
}

// ---- lift im2col (one batch): A[px][160] bf16 ----
__global__ void im2col_lift_k(const float* __restrict__ xb, __hip_bfloat16* __restrict__ A) {
    int idx = blockIdx.x * 256 + threadIdx.x;
    if (idx >= HW * 160) return;
    int px = idx / 160, k = idx % 160;
    float v = 0.f;
    if (k < 147) {
        int ci = k / 49, s = k % 49;
        int gy = mirror((px >> 8) + s / 7 - 3);
        int gx = mirror((px & 255) + s % 7 - 3);
        v = xb[ci * HW + gy * WID + gx];
    }
    A[idx] = __float2bfloat16(v);
}

// BN partial-sum reduction (8-acc 32x32 variant), verified R6..R9.
__device__ __forceinline__ void stats_reduce8(const float16* acc, int lane, int l31,
                                              float* sred) {
#pragma unroll
    for (int nt = 0; nt < 4; nt++) {
        float sv = 0.f, s2v = 0.f;
#pragma unroll
        for (int g = 0; g < 2; g++)
#pragma unroll
            for (int r = 0; r < 16; r++) {
                float v = acc[g * 4 + nt][r];
                sv += v;
                s2v += v * v;
            }
#pragma unroll
        for (int off = 1; off <= 4; off <<= 1) {
            sv += __shfl_xor(sv, off);
            s2v += __shfl_xor(s2v, off);
        }
        sv += __shfl_xor(sv, 32);
        s2v += __shfl_xor(s2v, 32);
        if ((lane & 39) == 0) {
            int c = nt * 4 + (l31 >> 3);
            atomicAdd(&sred[c], sv);
            atomicAdd(&sred[16 + c], s2v);
        }
    }
}

// lift GEMM: M=65536 (one b), K=160, N=128 -> RAW NHWC bf16 via LDS transpose.
__global__ __launch_bounds__(256, 2) void lift_gemm_k(const __hip_bfloat16* __restrict__ Ah,
                                                      const __hip_bfloat16* __restrict__ Bh,
                                                      __hip_bfloat16* __restrict__ nh_out,
                                                      float* __restrict__ stats) {
    __shared__ short tb[32768];   // [px_local 256][ch 128]
    __shared__ float sred[32];
    const short* A = (const short*)Ah;
    const short* B = (const short*)Bh;
    int tid = threadIdx.x;
    if (tid < 32) sred[tid] = 0.f;
    int wave = tid >> 6, lane = tid & 63;
    int l31 = lane & 31, half = lane >> 5;
    int p0 = blockIdx.x * 256 + wave * 64;
    float16 acc[8];
#pragma unroll
    for (int i = 0; i < 8; i++) acc[i] = (float16)0.f;
    const short* a0p = A + (size_t)(p0 + l31) * 160 + half * 8;
    const short* a1p = a0p + 32 * 160;
    const short* bp  = B + (size_t)l31 * 160 + half * 8;
#pragma unroll
    for (int ks = 0; ks < 10; ks++) {
        short8 a0 = *(const short8*)(a0p + ks * 16);
        short8 a1 = *(const short8*)(a1p + ks * 16);
#pragma unroll
        for (int nt = 0; nt < 4; nt++) {
            short8 bb = *(const short8*)(bp + nt * 32 * 160 + ks * 16);
            acc[nt]     = __builtin_amdgcn_mfma_f32_32x32x16_bf16(a0, bb, acc[nt], 0, 0, 0);
            acc[4 + nt] = __builtin_amdgcn_mfma_f32_32x32x16_bf16(a1, bb, acc[4 + nt], 0, 0, 0);
        }
    }
    // transpose to [px][ch] bf16 in LDS, then coalesced NHWC store
#pragma unroll
    for (int g = 0; g < 2; g++)
#pragma unroll
        for (int nt = 0; nt < 4; nt++) {
            int ch = nt * 32 + l31;
#pragma unroll
            for (int r4 = 0; r4 < 4; r4++) {
                int pxb = wave * 64 + g * 32 + 8 * r4 + 4 * half;
#pragma unroll
                for (int i = 0; i < 4; i++)
                    tb[(pxb + i) * 128 + ch] = f2b(acc[g * 4 + nt][r4 * 4 + i]);
            }
        }
    __syncthreads();
    short* outp = (short*)nh_out;
    int pbase = blockIdx.x * 256;
    for (int i = tid; i < 4096; i += 256) {   // 256 px x 16 seg
        int pxl = i >> 4, seg = i & 15;
        *(short8*)(outp + (size_t)(pbase + pxl) * NHWC_STRIDE + seg * 8) =
            *(const short8*)&tb[pxl * 128 + seg * 8];
    }
    stats_reduce8(acc, lane, l31, sred);
    __syncthreads();
    if (tid < 16) {
        atomicAdd(&stats[tid * 2], sred[tid]);
        atomicAdd(&stats[tid * 2 + 1], sred[16 + tid]);
    }
}

// gconv GEMM R10: R9 core (16x16x32, 4x4 acc, A-halo in LDS, B via L1,
// barrier-free s-loop) + BN+ReLU applied during staging (input is RAW NHWC)
// + RAW NHWC bf16 output via LDS transpose (Au reused). Fused stats.
__global__ __launch_bounds__(256, 3) void gconv_mfma_k(const __hip_bfloat16* __restrict__ nh_in,
                                                       const __hip_bfloat16* __restrict__ Bgh,
                                                       __hip_bfloat16* __restrict__ nh_out,
                                                       const float* __restrict__ statsPrev,
                                                       const float* __restrict__ gPrev,
                                                       const float* __restrict__ bPrev,
                                                       float* __restrict__ statsNew) {
    __shared__ short Au[16384];   // union: As halo (14112 used) | transpose (16384)
    __shared__ float ssl[32];
    __shared__ float sred[32];
    const short* nhwc = (const short*)nh_in;
    const short* Bg = (const short*)Bgh;
    int bid = blockIdx.x;
    int xcd = bid & 7, q2 = bid >> 3;
    int nhalf = q2 & 1, qt = q2 >> 1;
    int b = xcd >> 2, band = xcd & 3;
    int tx0 = (qt & 15) << 4;
    int ty0 = (band << 6) + ((qt >> 4) << 4);
    int tid = threadIdx.x;
    if (tid < 32) sred[tid] = 0.f;
    if (tid < 16) {   // BN finalize of the INPUT layer
        float mean = statsPrev[tid * 2] / BN_N;
        float var = statsPrev[tid * 2 + 1] / BN_N - mean * mean;
        float sc = gPrev[tid] * rsqrtf(var + 1e-5f);
        ssl[tid * 2] = sc;
        ssl[tid * 2 + 1] = bPrev[tid] - mean * sc;
    }
    int w = tid >> 6, lane = tid & 63;
    int l15 = lane & 15, l4 = lane >> 4;
    float4v acc[16];
#pragma unroll
    for (int i = 0; i < 16; i++) acc[i] = (float4v)0.f;
    const size_t bbase = (size_t)b * HW;
    const int nb = nhalf << 6;

    for (int q = 0; q < 4; q++) {
        __syncthreads();   // Au reuse guard (+ ssl/sred init at q=0)
        for (int i = tid; i < 1600; i += 256) {
            int kc = i / 400, p = i - kc * 400;
            int yl = p / 20, xl = p - yl * 20;
            int gy = mirror(ty0 - 2 + yl);
            int gx = mirror(tx0 - 2 + xl);
            short8 raw = *(const short8*)(nhwc + (bbase + gy * WID + gx) * NHWC_STRIDE
                                          + q * 32 + kc * 8);
            int c = q * 4 + kc;
            float sc = ssl[c * 2], sh = ssl[c * 2 + 1];
            short8 ov;
#pragma unroll
            for (int e = 0; e < 8; e++)
                ov[e] = f2b(fmaxf(fmaf(b2f(raw[e]), sc, sh), 0.f));
            *(short8*)&Au[(kc * 441 + yl * 21 + xl) * 8] = ov;
        }
        __syncthreads();
        for (int s = 0; s < 25; s++) {
            int dy = s / 5 - 2, dx = s % 5 - 2;
            int abase = l4 * 441 + ((w << 2) + 2 + dy) * 21 + (l15 + 2 + dx);
            const short* brow = Bg + ((size_t)(((q * 25 + s) << 2) + l4) * 128 + nb + l15) * 8;
            short8 a0 = *(const short8*)&Au[abase * 8];
            short8 a1 = *(const short8*)&Au[(abase + 21) * 8];
            short8 a2 = *(const short8*)&Au[(abase + 42) * 8];
            short8 a3 = *(const short8*)&Au[(abase + 63) * 8];
#pragma unroll
            for (int nt = 0; nt < 4; nt++) {
                short8 bb = *(const short8*)(brow + nt * 128);
                acc[nt]      = __builtin_amdgcn_mfma_f32_16x16x32_bf16(a0, bb, acc[nt], 0, 0, 0);
                acc[4 + nt]  = __builtin_amdgcn_mfma_f32_16x16x32_bf16(a1, bb, acc[4 + nt], 0, 0, 0);
                acc[8 + nt]  = __builtin_amdgcn_mfma_f32_16x16x32_bf16(a2, bb, acc[8 + nt], 0, 0, 0);
                acc[12 + nt] = __builtin_amdgcn_mfma_f32_16x16x32_bf16(a3, bb, acc[12 + nt], 0, 0, 0);
            }
        }
    }

    // ---- epilogue: transpose accs to [px][ch64] bf16 in Au, coalesced NHWC store
    __syncthreads();   // all waves done reading Au
#pragma unroll
    for (int ag = 0; ag < 4; ag++) {
        int pxb = ((w << 2) + ag) * 16 + (l4 << 2);
#pragma unroll
        for (int nt = 0; nt < 4; nt++) {
            int nl = nt * 16 + l15;
#pragma unroll
            for (int r = 0; r < 4; r++)
                Au[(pxb + r) * 64 + nl] = f2b(acc[ag * 4 + nt][r]);
        }
    }
    __syncthreads();
    short* outp = (short*)nh_out;
    for (int i = tid; i < 2048; i += 256) {   // 256 px x 8 seg
        int pxl = i >> 3, seg = i & 7;
        int y = ty0 + (pxl >> 4), x = tx0 + (pxl & 15);
        *(short8*)(outp + (bbase + y * WID + x) * NHWC_STRIDE + nb + seg * 8) =
            *(const short8*)&Au[pxl * 64 + seg * 8];
    }
    // BN partial sums: channel c = n>>3 = nhalf*8 + nt*2 + (l15>>3)
#pragma unroll
    for (int nt = 0; nt < 4; nt++) {
        float sv = 0.f, s2v = 0.f;
#pragma unroll
        for (int ag = 0; ag < 4; ag++)
#pragma unroll
            for (int r = 0; r < 4; r++) {
                float v = acc[ag * 4 + nt][r];
                sv += v;
                s2v += v * v;
            }
#pragma unroll
        for (int off = 1; off <= 4; off <<= 1) {
            sv += __shfl_xor(sv, off);
            s2v += __shfl_xor(s2v, off);
        }
        sv += __shfl_xor(sv, 16);
        s2v += __shfl_xor(s2v, 16);
        sv += __shfl_xor(sv, 32);
        s2v += __shfl_xor(s2v, 32);
        if ((lane & 7) == 0 && l4 == 0) {
            int c = (nhalf << 3) + (nt << 1) + (l15 >> 3);
            atomicAdd(&sred[c], sv);
            atomicAdd(&sred[16 + c], s2v);
        }
    }
    __syncthreads();
    if (tid < 16) {
        atomicAdd(&statsNew[tid * 2], sred[tid]);
        atomicAdd(&statsNew[tid * 2 + 1], sred[16 + tid]);
    }
}

// 1x1 gconv: RAW NHWC in (BN+ReLU inline on A) -> bf16 planar out + stats.
__global__ __launch_bounds__(256, 2) void conv1x1_gemm_k(const __hip_bfloat16* __restrict__ nh,
                                                         const __hip_bfloat16* __restrict__ B1h,
                                                         __hip_bfloat16* __restrict__ outP,
                                                         const float* __restrict__ statsPrev,
                                                         const float* __restrict__ gPrev,
                                                         const float* __restrict__ bPrev,
                                                         float* __restrict__ statsNew) {
    __shared__ float sred[32];
    __shared__ float ssl[32];
    const short* nhwc = (const short*)nh;
    const short* B1 = (const short*)B1h;
    int tid = threadIdx.x;
    if (tid < 32) sred[tid] = 0.f;
    if (tid < 16) {
        float mean = statsPrev[tid * 2] / BN_N;
        float var = statsPrev[tid * 2 + 1] / BN_N - mean * mean;
        float sc = gPrev[tid] * rsqrtf(var + 1e-5f);
        ssl[tid * 2] = sc;
        ssl[tid * 2 + 1] = bPrev[tid] - mean * sc;
    }
    __syncthreads();
    int b = blockIdx.y;
    int wave = tid >> 6, lane = tid & 63;
    int l31 = lane & 31, half = lane >> 5;
    int p0 = blockIdx.x * 256 + wave * 64;
    float16 acc[8];
#pragma unroll
    for (int i = 0; i < 8; i++) acc[i] = (float16)0.f;
    const short* a0p = nhwc + ((size_t)b * HW + p0 + l31) * NHWC_STRIDE + half * 8;
    const short* a1p = a0p + 32 * NHWC_STRIDE;
    const short* bp  = B1 + (size_t)l31 * 128 + half * 8;
#pragma unroll
    for (int ks = 0; ks < 8; ks++) {
        short8 r0 = *(const short8*)(a0p + ks * 16);
        short8 r1 = *(const short8*)(a1p + ks * 16);
        int c = ks * 2 + half;
        float sc = ssl[c * 2], sh = ssl[c * 2 + 1];
        short8 a0, a1;
#pragma unroll
        for (int e = 0; e < 8; e++) {
            a0[e] = f2b(fmaxf(fmaf(b2f(r0[e]), sc, sh), 0.f));
            a1[e] = f2b(fmaxf(fmaf(b2f(r1[e]), sc, sh), 0.f));
        }
#pragma unroll
        for (int nt = 0; nt < 4; nt++) {
            short8 bb = *(const short8*)(bp + nt * 32 * 128 + ks * 16);
            acc[nt]     = __builtin_amdgcn_mfma_f32_32x32x16_bf16(a0, bb, acc[nt], 0, 0, 0);
            acc[4 + nt] = __builtin_amdgcn_mfma_f32_32x32x16_bf16(a1, bb, acc[4 + nt], 0, 0, 0);
        }
    }
    short* outb = (short*)outP + (size_t)b * PLANE_B;
#pragma unroll
    for (int g = 0; g < 2; g++)
#pragma unroll
        for (int nt = 0; nt < 4; nt++) {
            int n = nt * 32 + l31;
#pragma unroll
            for (int r4 = 0; r4 < 4; r4++) {
                int base = 8 * r4 + 4 * half;
                short4v v;
                v[0] = f2b(acc[g * 4 + nt][r4 * 4 + 0]);
                v[1] = f2b(acc[g * 4 + nt][r4 * 4 + 1]);
                v[2] = f2b(acc[g * 4 + nt][r4 * 4 + 2]);
                v[3] = f2b(acc[g * 4 + nt][r4 * 4 + 3]);
                *(short4v*)(outb + (size_t)n * HW + p0 + g * 32 + base) = v;
            }
        }
    stats_reduce8(acc, lane, l31, sred);
    __syncthreads();
    if (tid < 16) {
        atomicAdd(&statsNew[tid * 2], sred[tid]);
        atomicAdd(&statsNew[tid * 2 + 1], sred[16 + tid]);
    }
}

// ---- BN-finalize + BN+ReLU on conv4 (bf16 planar), max over m, 1x1 + sigmoid ----
__global__ void final_k(const __hip_bfloat16* __restrict__ inP, const float* __restrict__ stats,
                        const float* __restrict__ g, const float* __restrict__ beta,
                        const float* __restrict__ fw, void* __restrict__ out,
                        const int* __restrict__ flag) {
    __shared__ float ssl[32];
    if (threadIdx.x < 16) {
        int c = threadIdx.x;
        float mean = stats[c * 2] / BN_N;
        float var = stats[c * 2 + 1] / BN_N - mean * mean;
        float sc = g[c] * rsqrtf(var + 1e-5f);
        ssl[c * 2] = sc;
        ssl[c * 2 + 1] = beta[c] - mean * sc;
    }
    __syncthreads();
    int i = blockIdx.x * blockDim.x + threadIdx.x;
    int b = i >> 16, pix = i & 65535;
    const short* inp = (const short*)inP;
    float acc = 0.f;
#pragma unroll
    for (int co = 0; co < 16; co++) {
        float sc = ssl[co * 2], sh = ssl[co * 2 + 1];
        float mx = 0.f;
        const short* p = inp + (size_t)b * PLANE_B + (size_t)co * PLANE_C + pix;
#pragma unroll
        for (int m = 0; m < 8; m++) mx = fmaxf(mx, fmaf(b2f(p[m * HW]), sc, sh));
        acc = fmaf(fw[co], mx, acc);
    }
    float r = 1.f / (1.f + expf(-acc));
    if (*flag)
        ((__hip_bfloat16*)out)[i] = __float2bfloat16(r);
    else
        ((float*)out)[i] = r;
}

extern "C" void kernel_launch(void* const* d_in, const int* in_sizes, int n_in,
                              void* d_out, int out_size, void* d_ws, size_t ws_size,
                              hipStream_t stream) {
    float* ws = (float*)d_ws;
    // conv4 planar bf16: 16,777,216 shorts = 8,388,608 f
    __hip_bfloat16* planarB = (__hip_bfloat16*)ws;
    __hip_bfloat16* nhwcA = (__hip_bfloat16*)(ws + 8388608);    // 8,912,896 f
    __hip_bfloat16* nhwcB = (__hip_bfloat16*)(ws + 17301504);   // 8,912,896 f
    __hip_bfloat16* Alift = nhwcB;                              // union: Alift dead before gconv1
    __hip_bfloat16* Bg    = (__hip_bfloat16*)(ws + 26214400);   // 204,800 f
    __hip_bfloat16* Blift = (__hip_bfloat16*)(ws + 26419200);   // 10,240 f
    __hip_bfloat16* B1    = (__hip_bfloat16*)(ws + 26429440);   // 8,192 f
    float* xF  = ws + 26437632;        // cvt region, 551,392 f
    float* lwF = xF + 393216;
    float* w1F = lwF + 2352;
    float* w2F = w1F + 51200;
    float* w3F = w2F + 51200;
    float* w4F = w3F + 51200;
    float* fwF = w4F + 2048;
    float* gbF = fwF + 16;             // 160 = g0,b0,...,g4,b4
    float* statsL = ws + 26989024;     // 5 x 32
    int*   flag   = (int*)(statsL + 160);

    detect_k<<<1, 256, 0, stream>>>(d_in[0], flag);
    cvt_all_k<<<(CVT_TOTAL + 511) / 512, 512, 0, stream>>>(
        d_in[0], d_in[1], d_in[2], d_in[3], d_in[4], d_in[5], d_in[6], d_in[7], d_in[8],
        d_in[9], d_in[10], d_in[11], d_in[12], d_in[13], d_in[14], d_in[15], d_in[16],
        xF, flag);

    // ---- lift: raw NHWC bf16 out + stats0 ----
    pack_blift_k<<<(128 * 160 + 255) / 256, 256, 0, stream>>>(lwF, Blift, statsL);
    for (int b = 0; b < 2; b++) {
        im2col_lift_k<<<(HW * 160 + 255) / 256, 256, 0, stream>>>(xF + (size_t)b * 3 * HW, Alift);
        lift_gemm_k<<<256, 256, 0, stream>>>(
            Alift, Blift,
            (__hip_bfloat16*)((short*)nhwcA + (size_t)b * HW * NHWC_STRIDE), statsL);
    }

    // ---- gconv 1..3: BN(prev) at staging, raw NHWC out + stats ----
    float* wlist[3] = {w1F, w2F, w3F};
    __hip_bfloat16* nio[4] = {nhwcA, nhwcB, nhwcA, nhwcB};
    for (int l = 0; l < 3; l++) {
        pack_bg_k<<<(409600 + 255) / 256, 256, 0, stream>>>(wlist[l], Bg, statsL + 32 * (l + 1));
        gconv_mfma_k<<<1024, 256, 0, stream>>>(nio[l], Bg, nio[l + 1],
                                               statsL + 32 * l, gbF + 32 * l, gbF + 32 * l + 16,
                                               statsL + 32 * (l + 1));
    }

    // ---- conv4 (1x1): BN3 inline, bf16 planar out + stats4 ----
    pack_b1_k<<<(128 * 128 + 255) / 256, 256, 0, stream>>>(w4F, B1, statsL + 128);
    conv1x1_gemm_k<<<dim3(256, 2), 256, 0, stream>>>(nio[3], B1, planarB,
                                                     statsL + 96, gbF + 96, gbF + 112,
                                                     statsL + 128);

    // ---- BN4 + max-project + final 1x1 + sigmoid ----
    final_k<<<(2 * HW) / 256, 256, 0, stream>>>(planarB, statsL + 128, gbF + 128, gbF + 144,
                                                fwF, d_out, flag);
}

// Round 11
// 502.839 us; speedup vs baseline: 2.2290x; 1.1095x over previous
//
#include <hip/hip_runtime.h>
#include <hip/hip_bf16.h>
#include <math.h>

// Between layers: NHWC bf16 RAW (pre-BN) [B][256*256][136] (ch=ci*8+o, pad->136).
// BN+ReLU applied during the NEXT layer's staging from fused batch stats.
#define HW 65536
#define WID 256
#define NOR 8
#define PLANE_C (NOR * HW)          // 524288
#define PLANE_B (16 * NOR * HW)     // 8388608
#define BN_N 1048576.0f
#define NHWC_STRIDE 136

typedef __attribute__((ext_vector_type(8)))  short  short8;
typedef __attribute__((ext_vector_type(4)))  short  short4v;
typedef __attribute__((ext_vector_type(16))) float  float16;
typedef __attribute__((ext_vector_type(4)))  float  float4v;

__device__ __forceinline__ float b2f(short s) {
    union { unsigned int u; float f; } c;
    c.u = ((unsigned int)(unsigned short)s) << 16;
    return c.f;
}
__device__ __forceinline__ short f2b(float f) {
    union { __hip_bfloat16 h; short s; } c;
    c.h = __float2bfloat16(f);
    return c.s;
}

// ---- runtime dtype detection (validated R2/R3) ----
__global__ void detect_k(const void* __restrict__ x, int* __restrict__ flag) {
    __shared__ int bad;
    if (threadIdx.x == 0) bad = 0;
    __syncthreads();
    const __hip_bfloat16* p = (const __hip_bfloat16*)x;
    for (int i = threadIdx.x; i < 4096; i += 256) {
        float v = __bfloat162float(p[i]);
        if (!(fabsf(v) < 1e4f)) atomicOr(&bad, 1);
    }
    __syncthreads();
    if (threadIdx.x == 0) *flag = bad ? 0 : 1;
}

// ---- all-inputs conversion (sizes verified R8) ----
#define CVT_TOTAL 551392
__global__ void cvt_all_k(const void* p0, const void* p1, const void* p2, const void* p3,
                          const void* p4, const void* p5, const void* p6, const void* p7,
                          const void* p8, const void* p9, const void* p10, const void* p11,
                          const void* p12, const void* p13, const void* p14, const void* p15,
                          const void* p16, float* __restrict__ dst, const int* __restrict__ flag) {
    int i = blockIdx.x * 512 + threadIdx.x;
    if (i >= CVT_TOTAL) return;
    const void* src; int off;
    if      (i < 393216) { src = p0;  off = 0; }
    else if (i < 395568) { src = p1;  off = 393216; }
    else if (i < 446768) { src = p2;  off = 395568; }
    else if (i < 497968) { src = p3;  off = 446768; }
    else if (i < 549168) { src = p4;  off = 497968; }
    else if (i < 551216) { src = p5;  off = 549168; }
    else if (i < 551232) { src = p6;  off = 551216; }
    else if (i < 551248) { src = p7;  off = 551232; }
    else if (i < 551264) { src = p8;  off = 551248; }
    else if (i < 551280) { src = p9;  off = 551264; }
    else if (i < 551296) { src = p10; off = 551280; }
    else if (i < 551312) { src = p11; off = 551296; }
    else if (i < 551328) { src = p12; off = 551312; }
    else if (i < 551344) { src = p13; off = 551328; }
    else if (i < 551360) { src = p14; off = 551344; }
    else if (i < 551376) { src = p15; off = 551360; }
    else                 { src = p16; off = 551376; }
    int j = i - off;
    dst[i] = (*flag) ? __bfloat162float(((const __hip_bfloat16*)src)[j])
                     : ((const float*)src)[j];
}

// ---- bilinear kernel rotation (bit-identical to R2..R10) ----
__device__ float rot_sample(const float* __restrict__ W, int k, float theta, int i, int j) {
    float c = 0.5f * (float)(k - 1);
    float ys = (float)i - c, xs = (float)j - c;
    float cs = cosf(theta), sn = sinf(theta);
    float sy = cs * ys - sn * xs + c;
    float sx = sn * ys + cs * xs + c;
    float fy = floorf(sy), fx = floorf(sx);
    int y0 = (int)fy, x0 = (int)fx;
    float wy = sy - fy, wx = sx - fx;
    float v00 = (y0 >= 0 && y0 < k && x0 >= 0 && x0 < k)                 ? W[y0 * k + x0]           : 0.f;
    float v01 = (y0 >= 0 && y0 < k && x0 + 1 >= 0 && x0 + 1 < k)         ? W[y0 * k + x0 + 1]       : 0.f;
    float v10 = (y0 + 1 >= 0 && y0 + 1 < k && x0 >= 0 && x0 < k)         ? W[(y0 + 1) * k + x0]     : 0.f;
    float v11 = (y0 + 1 >= 0 && y0 + 1 < k && x0 + 1 >= 0 && x0 + 1 < k) ? W[(y0 + 1) * k + x0 + 1] : 0.f;
    return v00 * (1 - wy) * (1 - wx) + v01 * (1 - wy) * wx
         + v10 * wy * (1 - wx) + v11 * wy * wx;
}

__device__ __forceinline__ float theta_of(int m) {
    return (6.2831855f * (float)m) / 8.0f;
}

__device__ __forceinline__ int mirror(int i) {
    i = i < 0 ? -i : i;
    return i >= WID ? (2 * WID - 2 - i) : i;
}

// ---- MEGA-PACK: all weight packs + all 5 layer stats zeroed, one dispatch ----
// Blift[n=c*8+o][k=ci*49+s pad 160]; Bg[q(4)][s(25)][kc4(4)][n(128)][j(8)],
// ch=q*32+kc4*8+j (R9 layout); B1[n][ch].
#define PK_BLIFT 20480
#define PK_BG 409600
#define PK_TOTAL (PK_BLIFT + 3 * PK_BG + 16384)
__global__ void mega_pack_k(const float* __restrict__ lwF, const float* __restrict__ w1F,
                            const float* __restrict__ w2F, const float* __restrict__ w3F,
                            const float* __restrict__ w4F,
                            __hip_bfloat16* __restrict__ Blift, __hip_bfloat16* __restrict__ Bg1,
                            __hip_bfloat16* __restrict__ Bg2, __hip_bfloat16* __restrict__ Bg3,
                            __hip_bfloat16* __restrict__ B1, float* __restrict__ statsL) {
    int idx = blockIdx.x * 256 + threadIdx.x;
    if (idx < 160) statsL[idx] = 0.f;
    if (idx >= PK_TOTAL) return;
    if (idx < PK_BLIFT) {
        int n = idx / 160, k = idx % 160;
        float v = 0.f;
        if (k < 147) {
            int c = n >> 3, o = n & 7;
            int ci = k / 49, s = k % 49;
            v = rot_sample(lwF + (c * 3 + ci) * 49, 7, theta_of(o), s / 7, s % 7);
        }
        Blift[idx] = __float2bfloat16(v);
        return;
    }
    idx -= PK_BLIFT;
    if (idx < 3 * PK_BG) {
        int l = idx / PK_BG;
        int r = idx - l * PK_BG;
        const float* w = (l == 0) ? w1F : ((l == 1) ? w2F : w3F);
        __hip_bfloat16* Bg = (l == 0) ? Bg1 : ((l == 1) ? Bg2 : Bg3);
        int j = r & 7;
        int n = (r >> 3) & 127;
        int kc4 = (r >> 10) & 3;
        int sq = r >> 12;
        int s = sq % 25, q = sq / 25;
        int ch = q * 32 + kc4 * 8 + j;
        int co = n >> 3, m = n & 7, ci = ch >> 3, o = ch & 7;
        int oo = (o - m + 8) & 7;
        Bg[r] = __float2bfloat16(
            rot_sample(w + ((co * 16 + ci) * 8 + oo) * 25, 5, theta_of(m), s / 5, s % 5));
        return;
    }
    idx -= 3 * PK_BG;
    {
        int n = idx >> 7, ch = idx & 127;
        int co = n >> 3, m = n & 7, ci = ch >> 3, o = ch & 7;
        B1[idx] = __float2bfloat16(w4F[(co * 16 + ci) * 8 + ((o - m + 8) & 7)]);
    }
}

// BN partial-sum reduction (8-acc 32x32 variant), verified R6..R10.
__device__ __forceinline__ void stats_reduce8(const float16* acc, int lane, int l31,
                                              float* sred) {
#pragma unroll
    for (int nt = 0; nt < 4; nt++) {
        float sv = 0.f, s2v = 0.f;
#pragma unroll
        for (int g = 0; g < 2; g++)
#pragma unroll
            for (int r = 0; r < 16; r++) {
                float v = acc[g * 4 + nt][r];
                sv += v;
                s2v += v * v;
            }
#pragma unroll
        for (int off = 1; off <= 4; off <<= 1) {
            sv += __shfl_xor(sv, off);
            s2v += __shfl_xor(s2v, off);
        }
        sv += __shfl_xor(sv, 32);
        s2v += __shfl_xor(s2v, 32);
        if ((lane & 39) == 0) {
            int c = nt * 4 + (l31 >> 3);
            atomicAdd(&sred[c], sv);
            atomicAdd(&sred[16 + c], s2v);
        }
    }
}

// ---- FUSED lift: x fp32 halo in LDS -> in-register A-frags -> MFMA -> raw NHWC.
// Replaces im2col + lift_gemm (saves ~42 MB of intermediate traffic).
// Wave = 64 px (2 groups of 32) x 128 n, 8 accs (32x32x16), block = 16x16 tile.
__global__ __launch_bounds__(256, 2) void lift_fused_k(const float* __restrict__ xF,
                                                       const __hip_bfloat16* __restrict__ Bh,
                                                       __hip_bfloat16* __restrict__ nh_out,
                                                       float* __restrict__ stats) {
    __shared__ float Xs[3 * 484];   // [ci][yl*22+xl], halo origin (-3,-3)
    __shared__ short tb[32768];     // transpose [px 256][ch 128]
    __shared__ float sred[32];
    const short* B = (const short*)Bh;
    int tid = threadIdx.x;
    if (tid < 32) sred[tid] = 0.f;
    int tile = blockIdx.x;
    int b = blockIdx.y;
    int tx0 = (tile & 15) << 4, ty0 = (tile >> 4) << 4;
    for (int i = tid; i < 1452; i += 256) {
        int ci = i / 484, p = i - ci * 484;
        int yl = p / 22, xl = p - yl * 22;
        int gy = mirror(ty0 - 3 + yl), gx = mirror(tx0 - 3 + xl);
        Xs[i] = xF[((size_t)b * 3 + ci) * HW + gy * WID + gx];
    }
    __syncthreads();
    int wave = tid >> 6, lane = tid & 63;
    int l31 = lane & 31, half = lane >> 5;
    float16 acc[8];
#pragma unroll
    for (int i = 0; i < 8; i++) acc[i] = (float16)0.f;
    int pxl0 = wave * 64 + l31;          // A group 0 px; group 1 = +32
    int py0 = pxl0 >> 4, px0 = pxl0 & 15;
    int py1 = (pxl0 + 32) >> 4, px1 = (pxl0 + 32) & 15;
    const short* bp = B + (size_t)l31 * 160 + half * 8;
#pragma unroll
    for (int ks = 0; ks < 10; ks++) {
        short8 a0, a1;
#pragma unroll
        for (int j = 0; j < 8; j++) {
            int k = ks * 16 + half * 8 + j;
            float v0 = 0.f, v1 = 0.f;
            if (k < 147) {
                int ci = (k < 49) ? 0 : ((k < 98) ? 1 : 2);
                int s = k - ci * 49;
                int sy = s / 7, sx = s - sy * 7;
                v0 = Xs[ci * 484 + (py0 + sy) * 22 + px0 + sx];
                v1 = Xs[ci * 484 + (py1 + sy) * 22 + px1 + sx];
            }
            a0[j] = f2b(v0);
            a1[j] = f2b(v1);
        }
#pragma unroll
        for (int nt = 0; nt < 4; nt++) {
            short8 bb = *(const short8*)(bp + nt * 32 * 160 + ks * 16);
            acc[nt]     = __builtin_amdgcn_mfma_f32_32x32x16_bf16(a0, bb, acc[nt], 0, 0, 0);
            acc[4 + nt] = __builtin_amdgcn_mfma_f32_32x32x16_bf16(a1, bb, acc[4 + nt], 0, 0, 0);
        }
    }
    // transpose to [px][ch] bf16, coalesced NHWC store
#pragma unroll
    for (int g = 0; g < 2; g++)
#pragma unroll
        for (int nt = 0; nt < 4; nt++) {
            int ch = nt * 32 + l31;
#pragma unroll
            for (int r4 = 0; r4 < 4; r4++) {
                int pxb = wave * 64 + g * 32 + 8 * r4 + 4 * half;
#pragma unroll
                for (int i = 0; i < 4; i++)
                    tb[(pxb + i) * 128 + ch] = f2b(acc[g * 4 + nt][r4 * 4 + i]);
            }
        }
    __syncthreads();
    short* outp = (short*)nh_out + (size_t)b * HW * NHWC_STRIDE;
    for (int i = tid; i < 4096; i += 256) {
        int pxl = i >> 4, seg = i & 15;
        int y = ty0 + (pxl >> 4), x = tx0 + (pxl & 15);
        *(short8*)(outp + ((size_t)y * WID + x) * NHWC_STRIDE + seg * 8) =
            *(const short8*)&tb[pxl * 128 + seg * 8];
    }
    stats_reduce8(acc, lane, l31, sred);
    __syncthreads();
    if (tid < 16) {
        atomicAdd(&stats[tid * 2], sred[tid]);
        atomicAdd(&stats[tid * 2 + 1], sred[16 + tid]);
    }
}

// gconv GEMM (R10, unchanged): 16x16x32, 4x4 acc, A-halo in LDS, B via L1,
// barrier-free s-loop, BN(prev) at staging, raw NHWC out, fused stats.
__global__ __launch_bounds__(256, 3) void gconv_mfma_k(const __hip_bfloat16* __restrict__ nh_in,
                                                       const __hip_bfloat16* __restrict__ Bgh,
                                                       __hip_bfloat16* __restrict__ nh_out,
                                                       const float* __restrict__ statsPrev,
                                                       const float* __restrict__ gPrev,
                                                       const float* __restrict__ bPrev,
                                                       float* __restrict__ statsNew) {
    __shared__ short Au[16384];
    __shared__ float ssl[32];
    __shared__ float sred[32];
    const short* nhwc = (const short*)nh_in;
    const short* Bg = (const short*)Bgh;
    int bid = blockIdx.x;
    int xcd = bid & 7, q2 = bid >> 3;
    int nhalf = q2 & 1, qt = q2 >> 1;
    int b = xcd >> 2, band = xcd & 3;
    int tx0 = (qt & 15) << 4;
    int ty0 = (band << 6) + ((qt >> 4) << 4);
    int tid = threadIdx.x;
    if (tid < 32) sred[tid] = 0.f;
    if (tid < 16) {
        float mean = statsPrev[tid * 2] / BN_N;
        float var = statsPrev[tid * 2 + 1] / BN_N - mean * mean;
        float sc = gPrev[tid] * rsqrtf(var + 1e-5f);
        ssl[tid * 2] = sc;
        ssl[tid * 2 + 1] = bPrev[tid] - mean * sc;
    }
    int w = tid >> 6, lane = tid & 63;
    int l15 = lane & 15, l4 = lane >> 4;
    float4v acc[16];
#pragma unroll
    for (int i = 0; i < 16; i++) acc[i] = (float4v)0.f;
    const size_t bbase = (size_t)b * HW;
    const int nb = nhalf << 6;

    for (int q = 0; q < 4; q++) {
        __syncthreads();
        for (int i = tid; i < 1600; i += 256) {
            int kc = i / 400, p = i - kc * 400;
            int yl = p / 20, xl = p - yl * 20;
            int gy = mirror(ty0 - 2 + yl);
            int gx = mirror(tx0 - 2 + xl);
            short8 raw = *(const short8*)(nhwc + (bbase + gy * WID + gx) * NHWC_STRIDE
                                          + q * 32 + kc * 8);
            int c = q * 4 + kc;
            float sc = ssl[c * 2], sh = ssl[c * 2 + 1];
            short8 ov;
#pragma unroll
            for (int e = 0; e < 8; e++)
                ov[e] = f2b(fmaxf(fmaf(b2f(raw[e]), sc, sh), 0.f));
            *(short8*)&Au[(kc * 441 + yl * 21 + xl) * 8] = ov;
        }
        __syncthreads();
        for (int s = 0; s < 25; s++) {
            int dy = s / 5 - 2, dx = s % 5 - 2;
            int abase = l4 * 441 + ((w << 2) + 2 + dy) * 21 + (l15 + 2 + dx);
            const short* brow = Bg + ((size_t)(((q * 25 + s) << 2) + l4) * 128 + nb + l15) * 8;
            short8 a0 = *(const short8*)&Au[abase * 8];
            short8 a1 = *(const short8*)&Au[(abase + 21) * 8];
            short8 a2 = *(const short8*)&Au[(abase + 42) * 8];
            short8 a3 = *(const short8*)&Au[(abase + 63) * 8];
#pragma unroll
            for (int nt = 0; nt < 4; nt++) {
                short8 bb = *(const short8*)(brow + nt * 128);
                acc[nt]      = __builtin_amdgcn_mfma_f32_16x16x32_bf16(a0, bb, acc[nt], 0, 0, 0);
                acc[4 + nt]  = __builtin_amdgcn_mfma_f32_16x16x32_bf16(a1, bb, acc[4 + nt], 0, 0, 0);
                acc[8 + nt]  = __builtin_amdgcn_mfma_f32_16x16x32_bf16(a2, bb, acc[8 + nt], 0, 0, 0);
                acc[12 + nt] = __builtin_amdgcn_mfma_f32_16x16x32_bf16(a3, bb, acc[12 + nt], 0, 0, 0);
            }
        }
    }

    __syncthreads();
#pragma unroll
    for (int ag = 0; ag < 4; ag++) {
        int pxb = ((w << 2) + ag) * 16 + (l4 << 2);
#pragma unroll
        for (int nt = 0; nt < 4; nt++) {
            int nl = nt * 16 + l15;
#pragma unroll
            for (int r = 0; r < 4; r++)
                Au[(pxb + r) * 64 + nl] = f2b(acc[ag * 4 + nt][r]);
        }
    }
    __syncthreads();
    short* outp = (short*)nh_out;
    for (int i = tid; i < 2048; i += 256) {
        int pxl = i >> 3, seg = i & 7;
        int y = ty0 + (pxl >> 4), x = tx0 + (pxl & 15);
        *(short8*)(outp + (bbase + y * WID + x) * NHWC_STRIDE + nb + seg * 8) =
            *(const short8*)&Au[pxl * 64 + seg * 8];
    }
#pragma unroll
    for (int nt = 0; nt < 4; nt++) {
        float sv = 0.f, s2v = 0.f;
#pragma unroll
        for (int ag = 0; ag < 4; ag++)
#pragma unroll
            for (int r = 0; r < 4; r++) {
                float v = acc[ag * 4 + nt][r];
                sv += v;
                s2v += v * v;
            }
#pragma unroll
        for (int off = 1; off <= 4; off <<= 1) {
            sv += __shfl_xor(sv, off);
            s2v += __shfl_xor(s2v, off);
        }
        sv += __shfl_xor(sv, 16);
        s2v += __shfl_xor(s2v, 16);
        sv += __shfl_xor(sv, 32);
        s2v += __shfl_xor(s2v, 32);
        if ((lane & 7) == 0 && l4 == 0) {
            int c = (nhalf << 3) + (nt << 1) + (l15 >> 3);
            atomicAdd(&sred[c], sv);
            atomicAdd(&sred[16 + c], s2v);
        }
    }
    __syncthreads();
    if (tid < 16) {
        atomicAdd(&statsNew[tid * 2], sred[tid]);
        atomicAdd(&statsNew[tid * 2 + 1], sred[16 + tid]);
    }
}

// 1x1 gconv (R10, unchanged): RAW NHWC in (BN+ReLU inline) -> bf16 planar + stats.
__global__ __launch_bounds__(256, 2) void conv1x1_gemm_k(const __hip_bfloat16* __restrict__ nh,
                                                         const __hip_bfloat16* __restrict__ B1h,
                                                         __hip_bfloat16* __restrict__ outP,
                                                         const float* __restrict__ statsPrev,
                                                         const float* __restrict__ gPrev,
                                                         const float* __restrict__ bPrev,
                                                         float* __restrict__ statsNew) {
    __shared__ float sred[32];
    __shared__ float ssl[32];
    const short* nhwc = (const short*)nh;
    const short* B1 = (const short*)B1h;
    int tid = threadIdx.x;
    if (tid < 32) sred[tid] = 0.f;
    if (tid < 16) {
        float mean = statsPrev[tid * 2] / BN_N;
        float var = statsPrev[tid * 2 + 1] / BN_N - mean * mean;
        float sc = gPrev[tid] * rsqrtf(var + 1e-5f);
        ssl[tid * 2] = sc;
        ssl[tid * 2 + 1] = bPrev[tid] - mean * sc;
    }
    __syncthreads();
    int b = blockIdx.y;
    int wave = tid >> 6, lane = tid & 63;
    int l31 = lane & 31, half = lane >> 5;
    int p0 = blockIdx.x * 256 + wave * 64;
    float16 acc[8];
#pragma unroll
    for (int i = 0; i < 8; i++) acc[i] = (float16)0.f;
    const short* a0p = nhwc + ((size_t)b * HW + p0 + l31) * NHWC_STRIDE + half * 8;
    const short* a1p = a0p + 32 * NHWC_STRIDE;
    const short* bp  = B1 + (size_t)l31 * 128 + half * 8;
#pragma unroll
    for (int ks = 0; ks < 8; ks++) {
        short8 r0 = *(const short8*)(a0p + ks * 16);
        short8 r1 = *(const short8*)(a1p + ks * 16);
        int c = ks * 2 + half;
        float sc = ssl[c * 2], sh = ssl[c * 2 + 1];
        short8 a0, a1;
#pragma unroll
        for (int e = 0; e < 8; e++) {
            a0[e] = f2b(fmaxf(fmaf(b2f(r0[e]), sc, sh), 0.f));
            a1[e] = f2b(fmaxf(fmaf(b2f(r1[e]), sc, sh), 0.f));
        }
#pragma unroll
        for (int nt = 0; nt < 4; nt++) {
            short8 bb = *(const short8*)(bp + nt * 32 * 128 + ks * 16);
            acc[nt]     = __builtin_amdgcn_mfma_f32_32x32x16_bf16(a0, bb, acc[nt], 0, 0, 0);
            acc[4 + nt] = __builtin_amdgcn_mfma_f32_32x32x16_bf16(a1, bb, acc[4 + nt], 0, 0, 0);
        }
    }
    short* outb = (short*)outP + (size_t)b * PLANE_B;
#pragma unroll
    for (int g = 0; g < 2; g++)
#pragma unroll
        for (int nt = 0; nt < 4; nt++) {
            int n = nt * 32 + l31;
#pragma unroll
            for (int r4 = 0; r4 < 4; r4++) {
                int base = 8 * r4 + 4 * half;
                short4v v;
                v[0] = f2b(acc[g * 4 + nt][r4 * 4 + 0]);
                v[1] = f2b(acc[g * 4 + nt][r4 * 4 + 1]);
                v[2] = f2b(acc[g * 4 + nt][r4 * 4 + 2]);
                v[3] = f2b(acc[g * 4 + nt][r4 * 4 + 3]);
                *(short4v*)(outb + (size_t)n * HW + p0 + g * 32 + base) = v;
            }
        }
    stats_reduce8(acc, lane, l31, sred);
    __syncthreads();
    if (tid < 16) {
        atomicAdd(&statsNew[tid * 2], sred[tid]);
        atomicAdd(&statsNew[tid * 2 + 1], sred[16 + tid]);
    }
}

// ---- BN-finalize + BN+ReLU on conv4 (bf16 planar), max over m, 1x1 + sigmoid ----
__global__ void final_k(const __hip_bfloat16* __restrict__ inP, const float* __restrict__ stats,
                        const float* __restrict__ g, const float* __restrict__ beta,
                        const float* __restrict__ fw, void* __restrict__ out,
                        const int* __restrict__ flag) {
    __shared__ float ssl[32];
    if (threadIdx.x < 16) {
        int c = threadIdx.x;
        float mean = stats[c * 2] / BN_N;
        float var = stats[c * 2 + 1] / BN_N - mean * mean;
        float sc = g[c] * rsqrtf(var + 1e-5f);
        ssl[c * 2] = sc;
        ssl[c * 2 + 1] = beta[c] - mean * sc;
    }
    __syncthreads();
    int i = blockIdx.x * blockDim.x + threadIdx.x;
    int b = i >> 16, pix = i & 65535;
    const short* inp = (const short*)inP;
    float acc = 0.f;
#pragma unroll
    for (int co = 0; co < 16; co++) {
        float sc = ssl[co * 2], sh = ssl[co * 2 + 1];
        float mx = 0.f;
        const short* p = inp + (size_t)b * PLANE_B + (size_t)co * PLANE_C + pix;
#pragma unroll
        for (int m = 0; m < 8; m++) mx = fmaxf(mx, fmaf(b2f(p[m * HW]), sc, sh));
        acc = fmaf(fw[co], mx, acc);
    }
    float r = 1.f / (1.f + expf(-acc));
    if (*flag)
        ((__hip_bfloat16*)out)[i] = __float2bfloat16(r);
    else
        ((float*)out)[i] = r;
}

extern "C" void kernel_launch(void* const* d_in, const int* in_sizes, int n_in,
                              void* d_out, int out_size, void* d_ws, size_t ws_size,
                              hipStream_t stream) {
    float* ws = (float*)d_ws;
    __hip_bfloat16* planarB = (__hip_bfloat16*)ws;              // 8,388,608 f
    __hip_bfloat16* nhwcA = (__hip_bfloat16*)(ws + 8388608);    // 8,912,896 f
    __hip_bfloat16* nhwcB = (__hip_bfloat16*)(ws + 17301504);   // 8,912,896 f
    __hip_bfloat16* Bg1   = (__hip_bfloat16*)(ws + 26214400);   // 204,800 f
    __hip_bfloat16* Bg2   = (__hip_bfloat16*)(ws + 26419200);   // 204,800 f
    __hip_bfloat16* Bg3   = (__hip_bfloat16*)(ws + 26624000);   // 204,800 f
    __hip_bfloat16* Blift = (__hip_bfloat16*)(ws + 26828800);   // 10,240 f
    __hip_bfloat16* B1    = (__hip_bfloat16*)(ws + 26839040);   // 8,192 f
    float* xF  = ws + 26847232;        // cvt region, 551,392 f
    float* lwF = xF + 393216;
    float* w1F = lwF + 2352;
    float* w2F = w1F + 51200;
    float* w3F = w2F + 51200;
    float* w4F = w3F + 51200;
    float* fwF = w4F + 2048;
    float* gbF = fwF + 16;             // 160 = g0,b0,...,g4,b4
    float* statsL = ws + 27398624;     // 5 x 32
    int*   flag   = (int*)(statsL + 160);

    detect_k<<<1, 256, 0, stream>>>(d_in[0], flag);
    cvt_all_k<<<(CVT_TOTAL + 511) / 512, 512, 0, stream>>>(
        d_in[0], d_in[1], d_in[2], d_in[3], d_in[4], d_in[5], d_in[6], d_in[7], d_in[8],
        d_in[9], d_in[10], d_in[11], d_in[12], d_in[13], d_in[14], d_in[15], d_in[16],
        xF, flag);

    // ---- one dispatch: all weight packs + all stats zeroed ----
    mega_pack_k<<<(PK_TOTAL + 255) / 256, 256, 0, stream>>>(
        lwF, w1F, w2F, w3F, w4F, Blift, Bg1, Bg2, Bg3, B1, statsL);

    // ---- fused lift: raw NHWC bf16 + stats0, one dispatch ----
    lift_fused_k<<<dim3(256, 2), 256, 0, stream>>>(xF, Blift, nhwcA, statsL);

    // ---- gconv 1..3: BN(prev) at staging, raw NHWC out + stats ----
    __hip_bfloat16* Bgs[3] = {Bg1, Bg2, Bg3};
    __hip_bfloat16* nio[4] = {nhwcA, nhwcB, nhwcA, nhwcB};
    for (int l = 0; l < 3; l++) {
        gconv_mfma_k<<<1024, 256, 0, stream>>>(nio[l], Bgs[l], nio[l + 1],
                                               statsL + 32 * l, gbF + 32 * l, gbF + 32 * l + 16,
                                               statsL + 32 * (l + 1));
    }

    // ---- conv4 (1x1): BN3 inline, bf16 planar out + stats4 ----
    conv1x1_gemm_k<<<dim3(256, 2), 256, 0, stream>>>(nio[3], B1, planarB,
                                                     statsL + 96, gbF + 96, gbF + 112,
                                                     statsL + 128);

    // ---- BN4 + max-project + final 1x1 + sigmoid ----
    final_k<<<(2 * HW) / 256, 256, 0, stream>>>(planarB, statsL + 128, gbF + 128, gbF + 144,
                                                fwF, d_out, flag);
}

// Round 12
// 458.052 us; speedup vs baseline: 2.4469x; 1.0978x over previous
//
#include <hip/hip_runtime.h>
#include <hip/hip_bf16.h>
#include <math.h>

// Between layers: NHWC bf16 RAW (pre-BN) [B][256*256][136] (ch=ci*8+o, pad->136).
// BN+ReLU applied during the NEXT layer's staging from fused batch stats.
#define HW 65536
#define WID 256
#define NOR 8
#define PLANE_C (NOR * HW)          // 524288
#define PLANE_B (16 * NOR * HW)     // 8388608
#define BN_N 1048576.0f
#define NHWC_STRIDE 136

typedef __attribute__((ext_vector_type(8)))  short  short8;
typedef __attribute__((ext_vector_type(4)))  short  short4v;
typedef __attribute__((ext_vector_type(16))) float  float16;
typedef __attribute__((ext_vector_type(4)))  float  float4v;

__device__ __forceinline__ float b2f(short s) {
    union { unsigned int u; float f; } c;
    c.u = ((unsigned int)(unsigned short)s) << 16;
    return c.f;
}
__device__ __forceinline__ short f2b(float f) {
    union { __hip_bfloat16 h; short s; } c;
    c.h = __float2bfloat16(f);
    return c.s;
}

// ---- runtime dtype detection (validated R2/R3) ----
__global__ void detect_k(const void* __restrict__ x, int* __restrict__ flag) {
    __shared__ int bad;
    if (threadIdx.x == 0) bad = 0;
    __syncthreads();
    const __hip_bfloat16* p = (const __hip_bfloat16*)x;
    for (int i = threadIdx.x; i < 4096; i += 256) {
        float v = __bfloat162float(p[i]);
        if (!(fabsf(v) < 1e4f)) atomicOr(&bad, 1);
    }
    __syncthreads();
    if (threadIdx.x == 0) *flag = bad ? 0 : 1;
}

// ---- all-inputs conversion (sizes verified R8) ----
#define CVT_TOTAL 551392
__global__ void cvt_all_k(const void* p0, const void* p1, const void* p2, const void* p3,
                          const void* p4, const void* p5, const void* p6, const void* p7,
                          const void* p8, const void* p9, const void* p10, const void* p11,
                          const void* p12, const void* p13, const void* p14, const void* p15,
                          const void* p16, float* __restrict__ dst, const int* __restrict__ flag) {
    int i = blockIdx.x * 512 + threadIdx.x;
    if (i >= CVT_TOTAL) return;
    const void* src; int off;
    if      (i < 393216) { src = p0;  off = 0; }
    else if (i < 395568) { src = p1;  off = 393216; }
    else if (i < 446768) { src = p2;  off = 395568; }
    else if (i < 497968) { src = p3;  off = 446768; }
    else if (i < 549168) { src = p4;  off = 497968; }
    else if (i < 551216) { src = p5;  off = 549168; }
    else if (i < 551232) { src = p6;  off = 551216; }
    else if (i < 551248) { src = p7;  off = 551232; }
    else if (i < 551264) { src = p8;  off = 551248; }
    else if (i < 551280) { src = p9;  off = 551264; }
    else if (i < 551296) { src = p10; off = 551280; }
    else if (i < 551312) { src = p11; off = 551296; }
    else if (i < 551328) { src = p12; off = 551312; }
    else if (i < 551344) { src = p13; off = 551328; }
    else if (i < 551360) { src = p14; off = 551344; }
    else if (i < 551376) { src = p15; off = 551360; }
    else                 { src = p16; off = 551376; }
    int j = i - off;
    dst[i] = (*flag) ? __bfloat162float(((const __hip_bfloat16*)src)[j])
                     : ((const float*)src)[j];
}

// ---- bilinear kernel rotation (bit-identical to R2..R11) ----
__device__ float rot_sample(const float* __restrict__ W, int k, float theta, int i, int j) {
    float c = 0.5f * (float)(k - 1);
    float ys = (float)i - c, xs = (float)j - c;
    float cs = cosf(theta), sn = sinf(theta);
    float sy = cs * ys - sn * xs + c;
    float sx = sn * ys + cs * xs + c;
    float fy = floorf(sy), fx = floorf(sx);
    int y0 = (int)fy, x0 = (int)fx;
    float wy = sy - fy, wx = sx - fx;
    float v00 = (y0 >= 0 && y0 < k && x0 >= 0 && x0 < k)                 ? W[y0 * k + x0]           : 0.f;
    float v01 = (y0 >= 0 && y0 < k && x0 + 1 >= 0 && x0 + 1 < k)         ? W[y0 * k + x0 + 1]       : 0.f;
    float v10 = (y0 + 1 >= 0 && y0 + 1 < k && x0 >= 0 && x0 < k)         ? W[(y0 + 1) * k + x0]     : 0.f;
    float v11 = (y0 + 1 >= 0 && y0 + 1 < k && x0 + 1 >= 0 && x0 + 1 < k) ? W[(y0 + 1) * k + x0 + 1] : 0.f;
    return v00 * (1 - wy) * (1 - wx) + v01 * (1 - wy) * wx
         + v10 * wy * (1 - wx) + v11 * wy * wx;
}

__device__ __forceinline__ float theta_of(int m) {
    return (6.2831855f * (float)m) / 8.0f;
}

__device__ __forceinline__ int mirror(int i) {
    i = i < 0 ? -i : i;
    return i >= WID ? (2 * WID - 2 - i) : i;
}

// ---- MEGA-PACK: all weight packs + all 5 layer stats zeroed, one dispatch ----
// Blift[n=c*8+o][k=ci*49+s pad 160]; Bg[q(4)][s(25)][kc4(4)][n(128)][j(8)],
// ch=q*32+kc4*8+j (R9 layout); B1[n][ch].
#define PK_BLIFT 20480
#define PK_BG 409600
#define PK_TOTAL (PK_BLIFT + 3 * PK_BG + 16384)
__global__ void mega_pack_k(const float* __restrict__ lwF, const float* __restrict__ w1F,
                            const float* __restrict__ w2F, const float* __restrict__ w3F,
                            const float* __restrict__ w4F,
                            __hip_bfloat16* __restrict__ Blift, __hip_bfloat16* __restrict__ Bg1,
                            __hip_bfloat16* __restrict__ Bg2, __hip_bfloat16* __restrict__ Bg3,
                            __hip_bfloat16* __restrict__ B1, float* __restrict__ statsL) {
    int idx = blockIdx.x * 256 + threadIdx.x;
    if (idx < 160) statsL[idx] = 0.f;
    if (idx >= PK_TOTAL) return;
    if (idx < PK_BLIFT) {
        int n = idx / 160, k = idx % 160;
        float v = 0.f;
        if (k < 147) {
            int c = n >> 3, o = n & 7;
            int ci = k / 49, s = k % 49;
            v = rot_sample(lwF + (c * 3 + ci) * 49, 7, theta_of(o), s / 7, s % 7);
        }
        Blift[idx] = __float2bfloat16(v);
        return;
    }
    idx -= PK_BLIFT;
    if (idx < 3 * PK_BG) {
        int l = idx / PK_BG;
        int r = idx - l * PK_BG;
        const float* w = (l == 0) ? w1F : ((l == 1) ? w2F : w3F);
        __hip_bfloat16* Bg = (l == 0) ? Bg1 : ((l == 1) ? Bg2 : Bg3);
        int j = r & 7;
        int n = (r >> 3) & 127;
        int kc4 = (r >> 10) & 3;
        int sq = r >> 12;
        int s = sq % 25, q = sq / 25;
        int ch = q * 32 + kc4 * 8 + j;
        int co = n >> 3, m = n & 7, ci = ch >> 3, o = ch & 7;
        int oo = (o - m + 8) & 7;
        Bg[r] = __float2bfloat16(
            rot_sample(w + ((co * 16 + ci) * 8 + oo) * 25, 5, theta_of(m), s / 5, s % 5));
        return;
    }
    idx -= 3 * PK_BG;
    {
        int n = idx >> 7, ch = idx & 127;
        int co = n >> 3, m = n & 7, ci = ch >> 3, o = ch & 7;
        B1[idx] = __float2bfloat16(w4F[(co * 16 + ci) * 8 + ((o - m + 8) & 7)]);
    }
}

// BN partial-sum reduction (8-acc 32x32 variant), verified R6..R11.
__device__ __forceinline__ void stats_reduce8(const float16* acc, int lane, int l31,
                                              float* sred) {
#pragma unroll
    for (int nt = 0; nt < 4; nt++) {
        float sv = 0.f, s2v = 0.f;
#pragma unroll
        for (int g = 0; g < 2; g++)
#pragma unroll
            for (int r = 0; r < 16; r++) {
                float v = acc[g * 4 + nt][r];
                sv += v;
                s2v += v * v;
            }
#pragma unroll
        for (int off = 1; off <= 4; off <<= 1) {
            sv += __shfl_xor(sv, off);
            s2v += __shfl_xor(s2v, off);
        }
        sv += __shfl_xor(sv, 32);
        s2v += __shfl_xor(s2v, 32);
        if ((lane & 39) == 0) {
            int c = nt * 4 + (l31 >> 3);
            atomicAdd(&sred[c], sv);
            atomicAdd(&sred[16 + c], s2v);
        }
    }
}

// ---- FUSED lift (R11, unchanged): x fp32 halo -> reg A-frags -> MFMA -> raw NHWC.
__global__ __launch_bounds__(256, 2) void lift_fused_k(const float* __restrict__ xF,
                                                       const __hip_bfloat16* __restrict__ Bh,
                                                       __hip_bfloat16* __restrict__ nh_out,
                                                       float* __restrict__ stats) {
    __shared__ float Xs[3 * 484];
    __shared__ short tb[32768];
    __shared__ float sred[32];
    const short* B = (const short*)Bh;
    int tid = threadIdx.x;
    if (tid < 32) sred[tid] = 0.f;
    int tile = blockIdx.x;
    int b = blockIdx.y;
    int tx0 = (tile & 15) << 4, ty0 = (tile >> 4) << 4;
    for (int i = tid; i < 1452; i += 256) {
        int ci = i / 484, p = i - ci * 484;
        int yl = p / 22, xl = p - yl * 22;
        int gy = mirror(ty0 - 3 + yl), gx = mirror(tx0 - 3 + xl);
        Xs[i] = xF[((size_t)b * 3 + ci) * HW + gy * WID + gx];
    }
    __syncthreads();
    int wave = tid >> 6, lane = tid & 63;
    int l31 = lane & 31, half = lane >> 5;
    float16 acc[8];
#pragma unroll
    for (int i = 0; i < 8; i++) acc[i] = (float16)0.f;
    int pxl0 = wave * 64 + l31;
    int py0 = pxl0 >> 4, px0 = pxl0 & 15;
    int py1 = (pxl0 + 32) >> 4, px1 = (pxl0 + 32) & 15;
    const short* bp = B + (size_t)l31 * 160 + half * 8;
#pragma unroll
    for (int ks = 0; ks < 10; ks++) {
        short8 a0, a1;
#pragma unroll
        for (int j = 0; j < 8; j++) {
            int k = ks * 16 + half * 8 + j;
            float v0 = 0.f, v1 = 0.f;
            if (k < 147) {
                int ci = (k < 49) ? 0 : ((k < 98) ? 1 : 2);
                int s = k - ci * 49;
                int sy = s / 7, sx = s - sy * 7;
                v0 = Xs[ci * 484 + (py0 + sy) * 22 + px0 + sx];
                v1 = Xs[ci * 484 + (py1 + sy) * 22 + px1 + sx];
            }
            a0[j] = f2b(v0);
            a1[j] = f2b(v1);
        }
#pragma unroll
        for (int nt = 0; nt < 4; nt++) {
            short8 bb = *(const short8*)(bp + nt * 32 * 160 + ks * 16);
            acc[nt]     = __builtin_amdgcn_mfma_f32_32x32x16_bf16(a0, bb, acc[nt], 0, 0, 0);
            acc[4 + nt] = __builtin_amdgcn_mfma_f32_32x32x16_bf16(a1, bb, acc[4 + nt], 0, 0, 0);
        }
    }
#pragma unroll
    for (int g = 0; g < 2; g++)
#pragma unroll
        for (int nt = 0; nt < 4; nt++) {
            int ch = nt * 32 + l31;
#pragma unroll
            for (int r4 = 0; r4 < 4; r4++) {
                int pxb = wave * 64 + g * 32 + 8 * r4 + 4 * half;
#pragma unroll
                for (int i = 0; i < 4; i++)
                    tb[(pxb + i) * 128 + ch] = f2b(acc[g * 4 + nt][r4 * 4 + i]);
            }
        }
    __syncthreads();
    short* outp = (short*)nh_out + (size_t)b * HW * NHWC_STRIDE;
    for (int i = tid; i < 4096; i += 256) {
        int pxl = i >> 4, seg = i & 15;
        int y = ty0 + (pxl >> 4), x = tx0 + (pxl & 15);
        *(short8*)(outp + ((size_t)y * WID + x) * NHWC_STRIDE + seg * 8) =
            *(const short8*)&tb[pxl * 128 + seg * 8];
    }
    stats_reduce8(acc, lane, l31, sred);
    __syncthreads();
    if (tid < 16) {
        atomicAdd(&stats[tid * 2], sred[tid]);
        atomicAdd(&stats[tid * 2 + 1], sred[16 + tid]);
    }
}

// gconv GEMM R12: grid 512 (one block per 16x16 tile, fully co-resident,
// 2 blocks/CU). Block = 256 thr = 4 waves; wave = 128 px (8 rows x 16) x 64 n,
// 8x4 acc tile (128 AGPR) -> reads/MFMA = 0.375 (12 loads per 32 MFMA).
// A-halo per kh-HALF (64 ch, padded [kc8][441][8]) in 64 KB LDS union with the
// 256x128 transpose buffer; staging re-reads halve, 4 barriers in main loop.
// B via L1 (4 KB slabs shared by waves). launch_bounds(256,2): 128 free VGPRs
// for deep prefetch. BN(prev) at staging; raw NHWC out; fused stats.
__global__ __launch_bounds__(256, 2) void gconv_mfma_k(const __hip_bfloat16* __restrict__ nh_in,
                                                       const __hip_bfloat16* __restrict__ Bgh,
                                                       __hip_bfloat16* __restrict__ nh_out,
                                                       const float* __restrict__ statsPrev,
                                                       const float* __restrict__ gPrev,
                                                       const float* __restrict__ bPrev,
                                                       float* __restrict__ statsNew) {
    __shared__ short Au[32768];   // union: halo [kc8][441][8] (28040 used) | transpose [256][128]
    __shared__ float ssl[32];
    __shared__ float sred[32];
    const short* nhwc = (const short*)nh_in;
    const short* Bg = (const short*)Bgh;
    int bid = blockIdx.x;              // 0..511
    int xcd = bid & 7, qt = bid >> 3;  // qt 0..63: tile in band
    int b = xcd >> 2, band = xcd & 3;
    int tx0 = (qt & 15) << 4;
    int ty0 = (band << 6) + ((qt >> 4) << 4);
    int tid = threadIdx.x;
    if (tid < 32) sred[tid] = 0.f;
    if (tid < 16) {   // BN finalize of the INPUT layer
        float mean = statsPrev[tid * 2] / BN_N;
        float var = statsPrev[tid * 2 + 1] / BN_N - mean * mean;
        float sc = gPrev[tid] * rsqrtf(var + 1e-5f);
        ssl[tid * 2] = sc;
        ssl[tid * 2 + 1] = bPrev[tid] - mean * sc;
    }
    int w = tid >> 6, lane = tid & 63;
    int pxg = w & 1, nhf = w >> 1;     // px-group (rows 8*pxg..+7), n-half
    int l15 = lane & 15, l4 = lane >> 4;
    float4v acc[32];
#pragma unroll
    for (int i = 0; i < 32; i++) acc[i] = (float4v)0.f;
    const size_t bbase = (size_t)b * HW;
    const int nb = nhf << 6;

    for (int h = 0; h < 2; h++) {
        __syncthreads();   // Au reuse guard (+ ssl/sred init at h=0)
        for (int i = tid; i < 3200; i += 256) {
            int kc = i / 400, p = i - kc * 400;
            int yl = p / 20, xl = p - yl * 20;
            int gy = mirror(ty0 - 2 + yl);
            int gx = mirror(tx0 - 2 + xl);
            short8 raw = *(const short8*)(nhwc + (bbase + gy * WID + gx) * NHWC_STRIDE
                                          + h * 64 + kc * 8);
            int c = h * 8 + kc;
            float sc = ssl[c * 2], sh = ssl[c * 2 + 1];
            short8 ov;
#pragma unroll
            for (int e = 0; e < 8; e++)
                ov[e] = f2b(fmaxf(fmaf(b2f(raw[e]), sc, sh), 0.f));
            *(short8*)&Au[(kc * 441 + yl * 21 + xl) * 8] = ov;
        }
        __syncthreads();
        for (int s = 0; s < 25; s++) {
            int dy = s / 5 - 2, dx = s % 5 - 2;
#pragma unroll
            for (int kq = 0; kq < 2; kq++) {
                int abase = (kq * 4 + l4) * 441 + ((pxg << 3) + 2 + dy) * 21 + (l15 + 2 + dx);
                const short* brow = Bg
                    + ((size_t)(((((h * 2 + kq) * 25 + s) << 2) + l4)) * 128 + nb + l15) * 8;
                short8 a[8];
#pragma unroll
                for (int r = 0; r < 8; r++)
                    a[r] = *(const short8*)&Au[(abase + r * 21) * 8];
#pragma unroll
                for (int nt = 0; nt < 4; nt++) {
                    short8 bb = *(const short8*)(brow + nt * 128);
#pragma unroll
                    for (int r = 0; r < 8; r++)
                        acc[r * 4 + nt] = __builtin_amdgcn_mfma_f32_16x16x32_bf16(
                            a[r], bb, acc[r * 4 + nt], 0, 0, 0);
                }
            }
        }
    }

    // ---- epilogue: transpose accs to [px 256][ch 128] bf16 in Au, coalesced NHWC store
    // C/D (16x16): col n = nb + nt*16 + l15; px-in-row = l4*4 + e; row = 8*pxg + r.
    __syncthreads();
#pragma unroll
    for (int r = 0; r < 8; r++) {
        int pxl = ((pxg << 3) + r) * 16 + (l4 << 2);
#pragma unroll
        for (int nt = 0; nt < 4; nt++) {
            int n = nb + nt * 16 + l15;
#pragma unroll
            for (int e = 0; e < 4; e++)
                Au[(pxl + e) * 128 + n] = f2b(acc[r * 4 + nt][e]);
        }
    }
    __syncthreads();
    short* outp = (short*)nh_out;
    for (int i = tid; i < 4096; i += 256) {   // 256 px x 16 seg
        int pxl = i >> 4, seg = i & 15;
        int y = ty0 + (pxl >> 4), x = tx0 + (pxl & 15);
        *(short8*)(outp + (bbase + y * WID + x) * NHWC_STRIDE + seg * 8) =
            *(const short8*)&Au[pxl * 128 + seg * 8];
    }
    // BN partial sums: channel c = n>>3 = nhf*8 + nt*2 + (l15>>3)
#pragma unroll
    for (int nt = 0; nt < 4; nt++) {
        float sv = 0.f, s2v = 0.f;
#pragma unroll
        for (int r = 0; r < 8; r++)
#pragma unroll
            for (int e = 0; e < 4; e++) {
                float v = acc[r * 4 + nt][e];
                sv += v;
                s2v += v * v;
            }
#pragma unroll
        for (int off = 1; off <= 4; off <<= 1) {
            sv += __shfl_xor(sv, off);
            s2v += __shfl_xor(s2v, off);
        }
        sv += __shfl_xor(sv, 16);
        s2v += __shfl_xor(s2v, 16);
        sv += __shfl_xor(sv, 32);
        s2v += __shfl_xor(s2v, 32);
        if ((lane & 7) == 0 && l4 == 0) {   // lanes 0, 8
            int c = (nhf << 3) + (nt << 1) + (l15 >> 3);
            atomicAdd(&sred[c], sv);
            atomicAdd(&sred[16 + c], s2v);
        }
    }
    __syncthreads();
    if (tid < 16) {
        atomicAdd(&statsNew[tid * 2], sred[tid]);
        atomicAdd(&statsNew[tid * 2 + 1], sred[16 + tid]);
    }
}

// 1x1 gconv (R10/R11, unchanged): RAW NHWC in (BN+ReLU inline) -> bf16 planar + stats.
__global__ __launch_bounds__(256, 2) void conv1x1_gemm_k(const __hip_bfloat16* __restrict__ nh,
                                                         const __hip_bfloat16* __restrict__ B1h,
                                                         __hip_bfloat16* __restrict__ outP,
                                                         const float* __restrict__ statsPrev,
                                                         const float* __restrict__ gPrev,
                                                         const float* __restrict__ bPrev,
                                                         float* __restrict__ statsNew) {
    __shared__ float sred[32];
    __shared__ float ssl[32];
    const short* nhwc = (const short*)nh;
    const short* B1 = (const short*)B1h;
    int tid = threadIdx.x;
    if (tid < 32) sred[tid] = 0.f;
    if (tid < 16) {
        float mean = statsPrev[tid * 2] / BN_N;
        float var = statsPrev[tid * 2 + 1] / BN_N - mean * mean;
        float sc = gPrev[tid] * rsqrtf(var + 1e-5f);
        ssl[tid * 2] = sc;
        ssl[tid * 2 + 1] = bPrev[tid] - mean * sc;
    }
    __syncthreads();
    int b = blockIdx.y;
    int wave = tid >> 6, lane = tid & 63;
    int l31 = lane & 31, half = lane >> 5;
    int p0 = blockIdx.x * 256 + wave * 64;
    float16 acc[8];
#pragma unroll
    for (int i = 0; i < 8; i++) acc[i] = (float16)0.f;
    const short* a0p = nhwc + ((size_t)b * HW + p0 + l31) * NHWC_STRIDE + half * 8;
    const short* a1p = a0p + 32 * NHWC_STRIDE;
    const short* bp  = B1 + (size_t)l31 * 128 + half * 8;
#pragma unroll
    for (int ks = 0; ks < 8; ks++) {
        short8 r0 = *(const short8*)(a0p + ks * 16);
        short8 r1 = *(const short8*)(a1p + ks * 16);
        int c = ks * 2 + half;
        float sc = ssl[c * 2], sh = ssl[c * 2 + 1];
        short8 a0, a1;
#pragma unroll
        for (int e = 0; e < 8; e++) {
            a0[e] = f2b(fmaxf(fmaf(b2f(r0[e]), sc, sh), 0.f));
            a1[e] = f2b(fmaxf(fmaf(b2f(r1[e]), sc, sh), 0.f));
        }
#pragma unroll
        for (int nt = 0; nt < 4; nt++) {
            short8 bb = *(const short8*)(bp + nt * 32 * 128 + ks * 16);
            acc[nt]     = __builtin_amdgcn_mfma_f32_32x32x16_bf16(a0, bb, acc[nt], 0, 0, 0);
            acc[4 + nt] = __builtin_amdgcn_mfma_f32_32x32x16_bf16(a1, bb, acc[4 + nt], 0, 0, 0);
        }
    }
    short* outb = (short*)outP + (size_t)b * PLANE_B;
#pragma unroll
    for (int g = 0; g < 2; g++)
#pragma unroll
        for (int nt = 0; nt < 4; nt++) {
            int n = nt * 32 + l31;
#pragma unroll
            for (int r4 = 0; r4 < 4; r4++) {
                int base = 8 * r4 + 4 * half;
                short4v v;
                v[0] = f2b(acc[g * 4 + nt][r4 * 4 + 0]);
                v[1] = f2b(acc[g * 4 + nt][r4 * 4 + 1]);
                v[2] = f2b(acc[g * 4 + nt][r4 * 4 + 2]);
                v[3] = f2b(acc[g * 4 + nt][r4 * 4 + 3]);
                *(short4v*)(outb + (size_t)n * HW + p0 + g * 32 + base) = v;
            }
        }
    stats_reduce8(acc, lane, l31, sred);
    __syncthreads();
    if (tid < 16) {
        atomicAdd(&statsNew[tid * 2], sred[tid]);
        atomicAdd(&statsNew[tid * 2 + 1], sred[16 + tid]);
    }
}

// ---- BN-finalize + BN+ReLU on conv4 (bf16 planar), max over m, 1x1 + sigmoid ----
__global__ void final_k(const __hip_bfloat16* __restrict__ inP, const float* __restrict__ stats,
                        const float* __restrict__ g, const float* __restrict__ beta,
                        const float* __restrict__ fw, void* __restrict__ out,
                        const int* __restrict__ flag) {
    __shared__ float ssl[32];
    if (threadIdx.x < 16) {
        int c = threadIdx.x;
        float mean = stats[c * 2] / BN_N;
        float var = stats[c * 2 + 1] / BN_N - mean * mean;
        float sc = g[c] * rsqrtf(var + 1e-5f);
        ssl[c * 2] = sc;
        ssl[c * 2 + 1] = beta[c] - mean * sc;
    }
    __syncthreads();
    int i = blockIdx.x * blockDim.x + threadIdx.x;
    int b = i >> 16, pix = i & 65535;
    const short* inp = (const short*)inP;
    float acc = 0.f;
#pragma unroll
    for (int co = 0; co < 16; co++) {
        float sc = ssl[co * 2], sh = ssl[co * 2 + 1];
        float mx = 0.f;
        const short* p = inp + (size_t)b * PLANE_B + (size_t)co * PLANE_C + pix;
#pragma unroll
        for (int m = 0; m < 8; m++) mx = fmaxf(mx, fmaf(b2f(p[m * HW]), sc, sh));
        acc = fmaf(fw[co], mx, acc);
    }
    float r = 1.f / (1.f + expf(-acc));
    if (*flag)
        ((__hip_bfloat16*)out)[i] = __float2bfloat16(r);
    else
        ((float*)out)[i] = r;
}

extern "C" void kernel_launch(void* const* d_in, const int* in_sizes, int n_in,
                              void* d_out, int out_size, void* d_ws, size_t ws_size,
                              hipStream_t stream) {
    float* ws = (float*)d_ws;
    __hip_bfloat16* planarB = (__hip_bfloat16*)ws;              // 8,388,608 f
    __hip_bfloat16* nhwcA = (__hip_bfloat16*)(ws + 8388608);    // 8,912,896 f
    __hip_bfloat16* nhwcB = (__hip_bfloat16*)(ws + 17301504);   // 8,912,896 f
    __hip_bfloat16* Bg1   = (__hip_bfloat16*)(ws + 26214400);   // 204,800 f
    __hip_bfloat16* Bg2   = (__hip_bfloat16*)(ws + 26419200);   // 204,800 f
    __hip_bfloat16* Bg3   = (__hip_bfloat16*)(ws + 26624000);   // 204,800 f
    __hip_bfloat16* Blift = (__hip_bfloat16*)(ws + 26828800);   // 10,240 f
    __hip_bfloat16* B1    = (__hip_bfloat16*)(ws + 26839040);   // 8,192 f
    float* xF  = ws + 26847232;        // cvt region, 551,392 f
    float* lwF = xF + 393216;
    float* w1F = lwF + 2352;
    float* w2F = w1F + 51200;
    float* w3F = w2F + 51200;
    float* w4F = w3F + 51200;
    float* fwF = w4F + 2048;
    float* gbF = fwF + 16;             // 160 = g0,b0,...,g4,b4
    float* statsL = ws + 27398624;     // 5 x 32
    int*   flag   = (int*)(statsL + 160);

    detect_k<<<1, 256, 0, stream>>>(d_in[0], flag);
    cvt_all_k<<<(CVT_TOTAL + 511) / 512, 512, 0, stream>>>(
        d_in[0], d_in[1], d_in[2], d_in[3], d_in[4], d_in[5], d_in[6], d_in[7], d_in[8],
        d_in[9], d_in[10], d_in[11], d_in[12], d_in[13], d_in[14], d_in[15], d_in[16],
        xF, flag);

    // ---- one dispatch: all weight packs + all stats zeroed ----
    mega_pack_k<<<(PK_TOTAL + 255) / 256, 256, 0, stream>>>(
        lwF, w1F, w2F, w3F, w4F, Blift, Bg1, Bg2, Bg3, B1, statsL);

    // ---- fused lift: raw NHWC bf16 + stats0 ----
    lift_fused_k<<<dim3(256, 2), 256, 0, stream>>>(xF, Blift, nhwcA, statsL);

    // ---- gconv 1..3: BN(prev) at staging, raw NHWC out + stats ----
    __hip_bfloat16* Bgs[3] = {Bg1, Bg2, Bg3};
    __hip_bfloat16* nio[4] = {nhwcA, nhwcB, nhwcA, nhwcB};
    for (int l = 0; l < 3; l++) {
        gconv_mfma_k<<<512, 256, 0, stream>>>(nio[l], Bgs[l], nio[l + 1],
                                              statsL + 32 * l, gbF + 32 * l, gbF + 32 * l + 16,
                                              statsL + 32 * (l + 1));
    }

    // ---- conv4 (1x1): BN3 inline, bf16 planar out + stats4 ----
    conv1x1_gemm_k<<<dim3(256, 2), 256, 0, stream>>>(nio[3], B1, planarB,
                                                     statsL + 96, gbF + 96, gbF + 112,
                                                     statsL + 128);

    // ---- BN4 + max-project + final 1x1 + sigmoid ----
    final_k<<<(2 * HW) / 256, 256, 0, stream>>>(planarB, statsL + 128, gbF + 128, gbF + 144,
                                                fwF, d_out, flag);
}

// Round 13
// 455.744 us; speedup vs baseline: 2.4593x; 1.0051x over previous
//
#include <hip/hip_runtime.h>
#include <hip/hip_bf16.h>
#include <math.h>

// Between layers: NHWC bf16 RAW (pre-BN) [B][256*256][136] (ch=ci*8+o, pad->136).
// BN+ReLU applied during the NEXT layer's staging from fused batch stats.
#define HW 65536
#define WID 256
#define NOR 8
#define PLANE_C (NOR * HW)          // 524288
#define PLANE_B (16 * NOR * HW)     // 8388608
#define BN_N 1048576.0f
#define NHWC_STRIDE 136

typedef __attribute__((ext_vector_type(8)))  short  short8;
typedef __attribute__((ext_vector_type(4)))  short  short4v;
typedef __attribute__((ext_vector_type(16))) float  float16;
typedef __attribute__((ext_vector_type(4)))  float  float4v;

__device__ __forceinline__ float b2f(short s) {
    union { unsigned int u; float f; } c;
    c.u = ((unsigned int)(unsigned short)s) << 16;
    return c.f;
}
__device__ __forceinline__ short f2b(float f) {
    union { __hip_bfloat16 h; short s; } c;
    c.h = __float2bfloat16(f);
    return c.s;
}
// dtype-flag-branched load: isbf=1 -> storage is bf16, else fp32
__device__ __forceinline__ float ldv(const void* p, int i, int isbf) {
    return isbf ? b2f(((const short*)p)[i]) : ((const float*)p)[i];
}

// ---- detect dtype + convert the 176 BN/fw scalars (one block) ----
__global__ void detect_cvt_k(const void* x, const void* fw,
                             const void* g0, const void* b0, const void* g1, const void* b1,
                             const void* g2, const void* b2, const void* g3, const void* b3,
                             const void* g4, const void* b4,
                             float* __restrict__ gbF, float* __restrict__ fwF,
                             int* __restrict__ flag) {
    __shared__ int bad;
    if (threadIdx.x == 0) bad = 0;
    __syncthreads();
    const __hip_bfloat16* p = (const __hip_bfloat16*)x;
    for (int i = threadIdx.x; i < 4096; i += 256) {
        float v = __bfloat162float(p[i]);
        if (!(fabsf(v) < 1e4f)) atomicOr(&bad, 1);
    }
    __syncthreads();
    int isbf = bad ? 0 : 1;
    if (threadIdx.x == 0) *flag = isbf;
    int t = threadIdx.x;
    if (t < 160) {
        const void* srcs[10] = {g0, b0, g1, b1, g2, b2, g3, b3, g4, b4};
        gbF[t] = ldv(srcs[t >> 4], t & 15, isbf);
    } else if (t < 176) {
        fwF[t - 160] = ldv(fw, t - 160, isbf);
    }
}

// ---- bilinear kernel rotation, flag-branched source (same math as R2..R12) ----
__device__ float rot_sample_g(const void* __restrict__ W, int isbf, int k, float theta,
                              int i, int j) {
    float c = 0.5f * (float)(k - 1);
    float ys = (float)i - c, xs = (float)j - c;
    float cs = cosf(theta), sn = sinf(theta);
    float sy = cs * ys - sn * xs + c;
    float sx = sn * ys + cs * xs + c;
    float fy = floorf(sy), fx = floorf(sx);
    int y0 = (int)fy, x0 = (int)fx;
    float wy = sy - fy, wx = sx - fx;
    float v00 = (y0 >= 0 && y0 < k && x0 >= 0 && x0 < k)                 ? ldv(W, y0 * k + x0, isbf)           : 0.f;
    float v01 = (y0 >= 0 && y0 < k && x0 + 1 >= 0 && x0 + 1 < k)         ? ldv(W, y0 * k + x0 + 1, isbf)       : 0.f;
    float v10 = (y0 + 1 >= 0 && y0 + 1 < k && x0 >= 0 && x0 < k)         ? ldv(W, (y0 + 1) * k + x0, isbf)     : 0.f;
    float v11 = (y0 + 1 >= 0 && y0 + 1 < k && x0 + 1 >= 0 && x0 + 1 < k) ? ldv(W, (y0 + 1) * k + x0 + 1, isbf) : 0.f;
    return v00 * (1 - wy) * (1 - wx) + v01 * (1 - wy) * wx
         + v10 * wy * (1 - wx) + v11 * wy * wx;
}

__device__ __forceinline__ float theta_of(int m) {
    return (6.2831855f * (float)m) / 8.0f;
}

__device__ __forceinline__ int mirror(int i) {
    i = i < 0 ? -i : i;
    return i >= WID ? (2 * WID - 2 - i) : i;
}

// ---- MEGA-PACK (flag-branched raw weights) + all 5 layer stats zeroed ----
// Blift[n=c*8+o][k=ci*49+s pad 160]; Bg[q(4)][s(25)][kc4(4)][n(128)][j(8)],
// ch=q*32+kc4*8+j; B1[n][ch].
#define PK_BLIFT 20480
#define PK_BG 409600
#define PK_TOTAL (PK_BLIFT + 3 * PK_BG + 16384)
__global__ void mega_pack_k(const void* __restrict__ lw, const void* __restrict__ w1,
                            const void* __restrict__ w2, const void* __restrict__ w3,
                            const void* __restrict__ w4,
                            __hip_bfloat16* __restrict__ Blift, __hip_bfloat16* __restrict__ Bg1,
                            __hip_bfloat16* __restrict__ Bg2, __hip_bfloat16* __restrict__ Bg3,
                            __hip_bfloat16* __restrict__ B1, float* __restrict__ statsL,
                            const int* __restrict__ flag) {
    int idx = blockIdx.x * 256 + threadIdx.x;
    if (idx < 160) statsL[idx] = 0.f;
    if (idx >= PK_TOTAL) return;
    int isbf = *flag;
    if (idx < PK_BLIFT) {
        int n = idx / 160, k = idx % 160;
        float v = 0.f;
        if (k < 147) {
            int c = n >> 3, o = n & 7;
            int ci = k / 49, s = k % 49;
            v = rot_sample_g((const char*)lw + 0, isbf, 7, theta_of(o), s / 7, s % 7);
            // base offset (c*3+ci)*49 applied via pointer arithmetic per dtype:
            v = rot_sample_g(isbf ? (const void*)((const short*)lw + (c * 3 + ci) * 49)
                                  : (const void*)((const float*)lw + (c * 3 + ci) * 49),
                             isbf, 7, theta_of(o), s / 7, s % 7);
        }
        Blift[idx] = __float2bfloat16(v);
        return;
    }
    idx -= PK_BLIFT;
    if (idx < 3 * PK_BG) {
        int l = idx / PK_BG;
        int r = idx - l * PK_BG;
        const void* w = (l == 0) ? w1 : ((l == 1) ? w2 : w3);
        __hip_bfloat16* Bg = (l == 0) ? Bg1 : ((l == 1) ? Bg2 : Bg3);
        int j = r & 7;
        int n = (r >> 3) & 127;
        int kc4 = (r >> 10) & 3;
        int sq = r >> 12;
        int s = sq % 25, q = sq / 25;
        int ch = q * 32 + kc4 * 8 + j;
        int co = n >> 3, m = n & 7, ci = ch >> 3, o = ch & 7;
        int oo = (o - m + 8) & 7;
        int off = ((co * 16 + ci) * 8 + oo) * 25;
        const void* wp = isbf ? (const void*)((const short*)w + off)
                              : (const void*)((const float*)w + off);
        Bg[r] = __float2bfloat16(rot_sample_g(wp, isbf, 5, theta_of(m), s / 5, s % 5));
        return;
    }
    idx -= 3 * PK_BG;
    {
        int n = idx >> 7, ch = idx & 127;
        int co = n >> 3, m = n & 7, ci = ch >> 3, o = ch & 7;
        B1[idx] = __float2bfloat16(ldv(w4, (co * 16 + ci) * 8 + ((o - m + 8) & 7), isbf));
    }
}

// BN partial-sum reduction (8-acc 32x32 variant), verified R6..R12.
__device__ __forceinline__ void stats_reduce8(const float16* acc, int lane, int l31,
                                              float* sred) {
#pragma unroll
    for (int nt = 0; nt < 4; nt++) {
        float sv = 0.f, s2v = 0.f;
#pragma unroll
        for (int g = 0; g < 2; g++)
#pragma unroll
            for (int r = 0; r < 16; r++) {
                float v = acc[g * 4 + nt][r];
                sv += v;
                s2v += v * v;
            }
#pragma unroll
        for (int off = 1; off <= 4; off <<= 1) {
            sv += __shfl_xor(sv, off);
            s2v += __shfl_xor(s2v, off);
        }
        sv += __shfl_xor(sv, 32);
        s2v += __shfl_xor(s2v, 32);
        if ((lane & 39) == 0) {
            int c = nt * 4 + (l31 >> 3);
            atomicAdd(&sred[c], sv);
            atomicAdd(&sred[16 + c], s2v);
        }
    }
}

// ---- FUSED lift (R11 core, x staged with flag-branched load) ----
__global__ __launch_bounds__(256, 2) void lift_fused_k(const void* __restrict__ x,
                                                       const __hip_bfloat16* __restrict__ Bh,
                                                       __hip_bfloat16* __restrict__ nh_out,
                                                       float* __restrict__ stats,
                                                       const int* __restrict__ flag) {
    __shared__ float Xs[3 * 484];
    __shared__ short tb[32768];
    __shared__ float sred[32];
    const short* B = (const short*)Bh;
    int tid = threadIdx.x;
    if (tid < 32) sred[tid] = 0.f;
    int isbf = *flag;
    int tile = blockIdx.x;
    int b = blockIdx.y;
    int tx0 = (tile & 15) << 4, ty0 = (tile >> 4) << 4;
    for (int i = tid; i < 1452; i += 256) {
        int ci = i / 484, p = i - ci * 484;
        int yl = p / 22, xl = p - yl * 22;
        int gy = mirror(ty0 - 3 + yl), gx = mirror(tx0 - 3 + xl);
        Xs[i] = ldv(x, (int)(((size_t)b * 3 + ci) * HW) + gy * WID + gx, isbf);
    }
    __syncthreads();
    int wave = tid >> 6, lane = tid & 63;
    int l31 = lane & 31, half = lane >> 5;
    float16 acc[8];
#pragma unroll
    for (int i = 0; i < 8; i++) acc[i] = (float16)0.f;
    int pxl0 = wave * 64 + l31;
    int py0 = pxl0 >> 4, px0 = pxl0 & 15;
    int py1 = (pxl0 + 32) >> 4, px1 = (pxl0 + 32) & 15;
    const short* bp = B + (size_t)l31 * 160 + half * 8;
#pragma unroll
    for (int ks = 0; ks < 10; ks++) {
        short8 a0, a1;
#pragma unroll
        for (int j = 0; j < 8; j++) {
            int k = ks * 16 + half * 8 + j;
            float v0 = 0.f, v1 = 0.f;
            if (k < 147) {
                int ci = (k < 49) ? 0 : ((k < 98) ? 1 : 2);
                int s = k - ci * 49;
                int sy = s / 7, sx = s - sy * 7;
                v0 = Xs[ci * 484 + (py0 + sy) * 22 + px0 + sx];
                v1 = Xs[ci * 484 + (py1 + sy) * 22 + px1 + sx];
            }
            a0[j] = f2b(v0);
            a1[j] = f2b(v1);
        }
#pragma unroll
        for (int nt = 0; nt < 4; nt++) {
            short8 bb = *(const short8*)(bp + nt * 32 * 160 + ks * 16);
            acc[nt]     = __builtin_amdgcn_mfma_f32_32x32x16_bf16(a0, bb, acc[nt], 0, 0, 0);
            acc[4 + nt] = __builtin_amdgcn_mfma_f32_32x32x16_bf16(a1, bb, acc[4 + nt], 0, 0, 0);
        }
    }
#pragma unroll
    for (int g = 0; g < 2; g++)
#pragma unroll
        for (int nt = 0; nt < 4; nt++) {
            int ch = nt * 32 + l31;
#pragma unroll
            for (int r4 = 0; r4 < 4; r4++) {
                int pxb = wave * 64 + g * 32 + 8 * r4 + 4 * half;
#pragma unroll
                for (int i = 0; i < 4; i++)
                    tb[(pxb + i) * 128 + ch] = f2b(acc[g * 4 + nt][r4 * 4 + i]);
            }
        }
    __syncthreads();
    short* outp = (short*)nh_out + (size_t)b * HW * NHWC_STRIDE;
    for (int i = tid; i < 4096; i += 256) {
        int pxl = i >> 4, seg = i & 15;
        int y = ty0 + (pxl >> 4), xx = tx0 + (pxl & 15);
        *(short8*)(outp + ((size_t)y * WID + xx) * NHWC_STRIDE + seg * 8) =
            *(const short8*)&tb[pxl * 128 + seg * 8];
    }
    stats_reduce8(acc, lane, l31, sred);
    __syncthreads();
    if (tid < 16) {
        atomicAdd(&stats[tid * 2], sred[tid]);
        atomicAdd(&stats[tid * 2 + 1], sred[16 + tid]);
    }
}

// gconv GEMM R13: R12 tile (wave = 128 px x 64 n, 8x4 acc) + dx-outer A-register
// caching: for each (kq,dx0) load 12 row-frags ONCE, reuse across 5 dy values
// -> A ds_reads drop 3.3x (1600->480 per block per h). Barrier-free s-loop,
// B via L1, BN(prev) at staging, raw NHWC out, fused stats.
__global__ __launch_bounds__(256, 2) void gconv_mfma_k(const __hip_bfloat16* __restrict__ nh_in,
                                                       const __hip_bfloat16* __restrict__ Bgh,
                                                       __hip_bfloat16* __restrict__ nh_out,
                                                       const float* __restrict__ statsPrev,
                                                       const float* __restrict__ gPrev,
                                                       const float* __restrict__ bPrev,
                                                       float* __restrict__ statsNew) {
    __shared__ short Au[32768];   // union: halo [kc8][441][8] (28040 used) | transpose [256][128]
    __shared__ float ssl[32];
    __shared__ float sred[32];
    const short* nhwc = (const short*)nh_in;
    const short* Bg = (const short*)Bgh;
    int bid = blockIdx.x;              // 0..511
    int xcd = bid & 7, qt = bid >> 3;
    int b = xcd >> 2, band = xcd & 3;
    int tx0 = (qt & 15) << 4;
    int ty0 = (band << 6) + ((qt >> 4) << 4);
    int tid = threadIdx.x;
    if (tid < 32) sred[tid] = 0.f;
    if (tid < 16) {
        float mean = statsPrev[tid * 2] / BN_N;
        float var = statsPrev[tid * 2 + 1] / BN_N - mean * mean;
        float sc = gPrev[tid] * rsqrtf(var + 1e-5f);
        ssl[tid * 2] = sc;
        ssl[tid * 2 + 1] = bPrev[tid] - mean * sc;
    }
    int w = tid >> 6, lane = tid & 63;
    int pxg = w & 1, nhf = w >> 1;
    int l15 = lane & 15, l4 = lane >> 4;
    float4v acc[32];
#pragma unroll
    for (int i = 0; i < 32; i++) acc[i] = (float4v)0.f;
    const size_t bbase = (size_t)b * HW;
    const int nb = nhf << 6;

    for (int h = 0; h < 2; h++) {
        __syncthreads();
        for (int i = tid; i < 3200; i += 256) {
            int kc = i / 400, p = i - kc * 400;
            int yl = p / 20, xl = p - yl * 20;
            int gy = mirror(ty0 - 2 + yl);
            int gx = mirror(tx0 - 2 + xl);
            short8 raw = *(const short8*)(nhwc + (bbase + gy * WID + gx) * NHWC_STRIDE
                                          + h * 64 + kc * 8);
            int c = h * 8 + kc;
            float sc = ssl[c * 2], sh = ssl[c * 2 + 1];
            short8 ov;
#pragma unroll
            for (int e = 0; e < 8; e++)
                ov[e] = f2b(fmaxf(fmaf(b2f(raw[e]), sc, sh), 0.f));
            *(short8*)&Au[(kc * 441 + yl * 21 + xl) * 8] = ov;
        }
        __syncthreads();
#pragma unroll
        for (int kq = 0; kq < 2; kq++) {
            int kcol = (kq * 4 + l4) * 441;
#pragma unroll
            for (int dx0 = 0; dx0 < 5; dx0++) {
                // 12 row-frags cover all dy for this column
                int base0 = kcol + (pxg << 3) * 21 + (l15 + dx0);
                short8 a[12];
#pragma unroll
                for (int rr = 0; rr < 12; rr++)
                    a[rr] = *(const short8*)&Au[(base0 + rr * 21) * 8];
#pragma unroll
                for (int dy0 = 0; dy0 < 5; dy0++) {
                    int s = dy0 * 5 + dx0;
                    const short* brow = Bg
                        + ((size_t)(((((h * 2 + kq) * 25 + s) << 2) + l4)) * 128 + nb + l15) * 8;
#pragma unroll
                    for (int nt = 0; nt < 4; nt++) {
                        short8 bb = *(const short8*)(brow + nt * 128);
#pragma unroll
                        for (int r = 0; r < 8; r++)
                            acc[r * 4 + nt] = __builtin_amdgcn_mfma_f32_16x16x32_bf16(
                                a[dy0 + r], bb, acc[r * 4 + nt], 0, 0, 0);
                    }
                }
            }
        }
    }

    // ---- epilogue: transpose accs to [px 256][ch 128] bf16 in Au, coalesced NHWC store
    __syncthreads();
#pragma unroll
    for (int r = 0; r < 8; r++) {
        int pxl = ((pxg << 3) + r) * 16 + (l4 << 2);
#pragma unroll
        for (int nt = 0; nt < 4; nt++) {
            int n = nb + nt * 16 + l15;
#pragma unroll
            for (int e = 0; e < 4; e++)
                Au[(pxl + e) * 128 + n] = f2b(acc[r * 4 + nt][e]);
        }
    }
    __syncthreads();
    short* outp = (short*)nh_out;
    for (int i = tid; i < 4096; i += 256) {
        int pxl = i >> 4, seg = i & 15;
        int y = ty0 + (pxl >> 4), x = tx0 + (pxl & 15);
        *(short8*)(outp + (bbase + y * WID + x) * NHWC_STRIDE + seg * 8) =
            *(const short8*)&Au[pxl * 128 + seg * 8];
    }
    // BN partial sums: channel c = nhf*8 + nt*2 + (l15>>3)
#pragma unroll
    for (int nt = 0; nt < 4; nt++) {
        float sv = 0.f, s2v = 0.f;
#pragma unroll
        for (int r = 0; r < 8; r++)
#pragma unroll
            for (int e = 0; e < 4; e++) {
                float v = acc[r * 4 + nt][e];
                sv += v;
                s2v += v * v;
            }
#pragma unroll
        for (int off = 1; off <= 4; off <<= 1) {
            sv += __shfl_xor(sv, off);
            s2v += __shfl_xor(s2v, off);
        }
        sv += __shfl_xor(sv, 16);
        s2v += __shfl_xor(s2v, 16);
        sv += __shfl_xor(sv, 32);
        s2v += __shfl_xor(s2v, 32);
        if ((lane & 7) == 0 && l4 == 0) {
            int c = (nhf << 3) + (nt << 1) + (l15 >> 3);
            atomicAdd(&sred[c], sv);
            atomicAdd(&sred[16 + c], s2v);
        }
    }
    __syncthreads();
    if (tid < 16) {
        atomicAdd(&statsNew[tid * 2], sred[tid]);
        atomicAdd(&statsNew[tid * 2 + 1], sred[16 + tid]);
    }
}

// 1x1 gconv (R10..R12, unchanged): RAW NHWC in (BN+ReLU inline) -> bf16 planar + stats.
__global__ __launch_bounds__(256, 2) void conv1x1_gemm_k(const __hip_bfloat16* __restrict__ nh,
                                                         const __hip_bfloat16* __restrict__ B1h,
                                                         __hip_bfloat16* __restrict__ outP,
                                                         const float* __restrict__ statsPrev,
                                                         const float* __restrict__ gPrev,
                                                         const float* __restrict__ bPrev,
                                                         float* __restrict__ statsNew) {
    __shared__ float sred[32];
    __shared__ float ssl[32];
    const short* nhwc = (const short*)nh;
    const short* B1 = (const short*)B1h;
    int tid = threadIdx.x;
    if (tid < 32) sred[tid] = 0.f;
    if (tid < 16) {
        float mean = statsPrev[tid * 2] / BN_N;
        float var = statsPrev[tid * 2 + 1] / BN_N - mean * mean;
        float sc = gPrev[tid] * rsqrtf(var + 1e-5f);
        ssl[tid * 2] = sc;
        ssl[tid * 2 + 1] = bPrev[tid] - mean * sc;
    }
    __syncthreads();
    int b = blockIdx.y;
    int wave = tid >> 6, lane = tid & 63;
    int l31 = lane & 31, half = lane >> 5;
    int p0 = blockIdx.x * 256 + wave * 64;
    float16 acc[8];
#pragma unroll
    for (int i = 0; i < 8; i++) acc[i] = (float16)0.f;
    const short* a0p = nhwc + ((size_t)b * HW + p0 + l31) * NHWC_STRIDE + half * 8;
    const short* a1p = a0p + 32 * NHWC_STRIDE;
    const short* bp  = B1 + (size_t)l31 * 128 + half * 8;
#pragma unroll
    for (int ks = 0; ks < 8; ks++) {
        short8 r0 = *(const short8*)(a0p + ks * 16);
        short8 r1 = *(const short8*)(a1p + ks * 16);
        int c = ks * 2 + half;
        float sc = ssl[c * 2], sh = ssl[c * 2 + 1];
        short8 a0, a1;
#pragma unroll
        for (int e = 0; e < 8; e++) {
            a0[e] = f2b(fmaxf(fmaf(b2f(r0[e]), sc, sh), 0.f));
            a1[e] = f2b(fmaxf(fmaf(b2f(r1[e]), sc, sh), 0.f));
        }
#pragma unroll
        for (int nt = 0; nt < 4; nt++) {
            short8 bb = *(const short8*)(bp + nt * 32 * 128 + ks * 16);
            acc[nt]     = __builtin_amdgcn_mfma_f32_32x32x16_bf16(a0, bb, acc[nt], 0, 0, 0);
            acc[4 + nt] = __builtin_amdgcn_mfma_f32_32x32x16_bf16(a1, bb, acc[4 + nt], 0, 0, 0);
        }
    }
    short* outb = (short*)outP + (size_t)b * PLANE_B;
#pragma unroll
    for (int g = 0; g < 2; g++)
#pragma unroll
        for (int nt = 0; nt < 4; nt++) {
            int n = nt * 32 + l31;
#pragma unroll
            for (int r4 = 0; r4 < 4; r4++) {
                int base = 8 * r4 + 4 * half;
                short4v v;
                v[0] = f2b(acc[g * 4 + nt][r4 * 4 + 0]);
                v[1] = f2b(acc[g * 4 + nt][r4 * 4 + 1]);
                v[2] = f2b(acc[g * 4 + nt][r4 * 4 + 2]);
                v[3] = f2b(acc[g * 4 + nt][r4 * 4 + 3]);
                *(short4v*)(outb + (size_t)n * HW + p0 + g * 32 + base) = v;
            }
        }
    stats_reduce8(acc, lane, l31, sred);
    __syncthreads();
    if (tid < 16) {
        atomicAdd(&statsNew[tid * 2], sred[tid]);
        atomicAdd(&statsNew[tid * 2 + 1], sred[16 + tid]);
    }
}

// ---- BN-finalize + BN+ReLU on conv4 (bf16 planar), max over m, 1x1 + sigmoid ----
__global__ void final_k(const __hip_bfloat16* __restrict__ inP, const float* __restrict__ stats,
                        const float* __restrict__ g, const float* __restrict__ beta,
                        const float* __restrict__ fw, void* __restrict__ out,
                        const int* __restrict__ flag) {
    __shared__ float ssl[32];
    if (threadIdx.x < 16) {
        int c = threadIdx.x;
        float mean = stats[c * 2] / BN_N;
        float var = stats[c * 2 + 1] / BN_N - mean * mean;
        float sc = g[c] * rsqrtf(var + 1e-5f);
        ssl[c * 2] = sc;
        ssl[c * 2 + 1] = beta[c] - mean * sc;
    }
    __syncthreads();
    int i = blockIdx.x * blockDim.x + threadIdx.x;
    int b = i >> 16, pix = i & 65535;
    const short* inp = (const short*)inP;
    float acc = 0.f;
#pragma unroll
    for (int co = 0; co < 16; co++) {
        float sc = ssl[co * 2], sh = ssl[co * 2 + 1];
        float mx = 0.f;
        const short* p = inp + (size_t)b * PLANE_B + (size_t)co * PLANE_C + pix;
#pragma unroll
        for (int m = 0; m < 8; m++) mx = fmaxf(mx, fmaf(b2f(p[m * HW]), sc, sh));
        acc = fmaf(fw[co], mx, acc);
    }
    float r = 1.f / (1.f + expf(-acc));
    if (*flag)
        ((__hip_bfloat16*)out)[i] = __float2bfloat16(r);
    else
        ((float*)out)[i] = r;
}

extern "C" void kernel_launch(void* const* d_in, const int* in_sizes, int n_in,
                              void* d_out, int out_size, void* d_ws, size_t ws_size,
                              hipStream_t stream) {
    float* ws = (float*)d_ws;
    __hip_bfloat16* planarB = (__hip_bfloat16*)ws;              // 8,388,608 f
    __hip_bfloat16* nhwcA = (__hip_bfloat16*)(ws + 8388608);    // 8,912,896 f
    __hip_bfloat16* nhwcB = (__hip_bfloat16*)(ws + 17301504);   // 8,912,896 f
    __hip_bfloat16* Bg1   = (__hip_bfloat16*)(ws + 26214400);   // 204,800 f
    __hip_bfloat16* Bg2   = (__hip_bfloat16*)(ws + 26419200);   // 204,800 f
    __hip_bfloat16* Bg3   = (__hip_bfloat16*)(ws + 26624000);   // 204,800 f
    __hip_bfloat16* Blift = (__hip_bfloat16*)(ws + 26828800);   // 10,240 f
    __hip_bfloat16* B1    = (__hip_bfloat16*)(ws + 26839040);   // 8,192 f
    float* gbF  = ws + 26847232;       // 160 = g0,b0,...,g4,b4 (converted fp32)
    float* fwF  = gbF + 160;           // 16
    float* statsL = fwF + 16;          // 5 x 32
    int*   flag   = (int*)(statsL + 160);

    detect_cvt_k<<<1, 256, 0, stream>>>(d_in[0], d_in[6],
                                        d_in[7], d_in[8], d_in[9], d_in[10], d_in[11],
                                        d_in[12], d_in[13], d_in[14], d_in[15], d_in[16],
                                        gbF, fwF, flag);

    // ---- one dispatch: all weight packs (flag-branched) + all stats zeroed ----
    mega_pack_k<<<(PK_TOTAL + 255) / 256, 256, 0, stream>>>(
        d_in[1], d_in[2], d_in[3], d_in[4], d_in[5],
        Blift, Bg1, Bg2, Bg3, B1, statsL, flag);

    // ---- fused lift: raw NHWC bf16 + stats0 ----
    lift_fused_k<<<dim3(256, 2), 256, 0, stream>>>(d_in[0], Blift, nhwcA, statsL, flag);

    // ---- gconv 1..3: BN(prev) at staging, raw NHWC out + stats ----
    __hip_bfloat16* Bgs[3] = {Bg1, Bg2, Bg3};
    __hip_bfloat16* nio[4] = {nhwcA, nhwcB, nhwcA, nhwcB};
    for (int l = 0; l < 3; l++) {
        gconv_mfma_k<<<512, 256, 0, stream>>>(nio[l], Bgs[l], nio[l + 1],
                                              statsL + 32 * l, gbF + 32 * l, gbF + 32 * l + 16,
                                              statsL + 32 * (l + 1));
    }

    // ---- conv4 (1x1): BN3 inline, bf16 planar out + stats4 ----
    conv1x1_gemm_k<<<dim3(256, 2), 256, 0, stream>>>(nio[3], B1, planarB,
                                                     statsL + 96, gbF + 96, gbF + 112,
                                                     statsL + 128);

    // ---- BN4 + max-project + final 1x1 + sigmoid ----
    final_k<<<(2 * HW) / 256, 256, 0, stream>>>(planarB, statsL + 128, gbF + 128, gbF + 144,
                                                fwF, d_out, flag);
}